// Round 17
// baseline (1038.711 us; speedup 1.0000x reference)
//
#include <hip/hip_runtime.h>
#include <hip/hip_bf16.h>

#define BB 16
#define NN 1024
#define BN (BB*NN)
#define KK 20
#define MARGIN 25   // fp32 prefilter width (>= KK + safety)

typedef short bf16x8v __attribute__((ext_vector_type(8)));
typedef float f32x4   __attribute__((ext_vector_type(4)));

// monotone float <-> uint key for atomic max/min (handles negatives)
__device__ inline unsigned fkey(float x) {
    unsigned b = __float_as_uint(x);
    return (b & 0x80000000u) ? ~b : (b | 0x80000000u);
}
__device__ inline float funkey(unsigned k) {
    unsigned b = (k & 0x80000000u) ? (k ^ 0x80000000u) : ~k;
    return __uint_as_float(b);
}
// fp32 -> bf16 bits, round-to-nearest-even
__device__ inline unsigned short f2bf(float x) {
    unsigned u = __float_as_uint(x);
    return (unsigned short)((u + 0x7FFFu + ((u >> 16) & 1u)) >> 16);
}

// XCD-aware swizzle (L1-3 gather): 1024 blocks = 16 batches x 64 subs.
__device__ inline void xcd_decode(int p, int& batch, int& s) {
    int xcd = p & 7, rem = p >> 3;
    s = rem & 63;
    batch = xcd + ((rem >> 6) << 3);
}

// ============ cast pos -> double + row sqnorm (fp64 + fp32) ============
__global__ void k_cast3(const float* __restrict__ pos, double* __restrict__ xd,
                        double* __restrict__ sqd, float* __restrict__ sqf) {
    int gn = blockIdx.x * blockDim.x + threadIdx.x;
    if (gn >= BN) return;
    double s = 0.0;
    #pragma unroll
    for (int c = 0; c < 3; ++c) {
        double v = (double)pos[gn * 3 + c];
        xd[gn * 3 + c] = v;
        s += v * v;
    }
    sqd[gn] = s;
    sqf[gn] = (float)s;
}

// ============ prep: fp64 y -> fp32 copy + sqnorms (fp64 + fp32) ============
__global__ void k_prep(const double* __restrict__ y, float* __restrict__ yf,
                       double* __restrict__ sqd, float* __restrict__ sqf, int C) {
    const int row = blockIdx.x * 4 + (threadIdx.x >> 6);
    const int lane = threadIdx.x & 63;
    const double* yr = y + (size_t)row * C;
    float* yfr = yf + (size_t)row * C;
    double s = 0.0;
    for (int c = lane; c < C; c += 64) {
        double v = yr[c];
        s += v * v;
        yfr[c] = (float)v;
    }
    #pragma unroll
    for (int off = 32; off > 0; off >>= 1) s += __shfl_xor(s, off, 64);
    if (lane == 0) { sqd[row] = s; sqf[row] = (float)s; }
}

// ============ W4 prep: transpose + bf16 + diff. W(256x1024) -> Wtb/Wdb [1024][128] ============
__global__ __launch_bounds__(256) void k_wprep(const float* __restrict__ W,
                                               unsigned short* __restrict__ Wtb,
                                               unsigned short* __restrict__ Wdb) {
    __shared__ float Lt[32][65], Ld[32][65];
    const int n0 = blockIdx.x * 64, k0 = blockIdx.y * 32;
    const int tid = threadIdx.x;
    {
        const int nn = tid & 63, kg = tid >> 6;
        #pragma unroll
        for (int i = 0; i < 8; ++i) {
            int kk = kg * 8 + i;
            float wt = W[(size_t)(k0 + kk) * 1024 + n0 + nn];
            float wb = W[(size_t)(128 + k0 + kk) * 1024 + n0 + nn];
            Lt[kk][nn] = wt;
            Ld[kk][nn] = wb - wt;
        }
    }
    __syncthreads();
    {
        const int kk = tid & 31, ng = tid >> 5;
        #pragma unroll
        for (int i = 0; i < 8; ++i) {
            int nl = ng + i * 8;
            Wtb[(size_t)(n0 + nl) * 128 + k0 + kk] = f2bf(Lt[kk][nl]);
            Wdb[(size_t)(n0 + nl) * 128 + k0 + kk] = f2bf(Ld[kk][nl]);
        }
    }
}

// ============ Yb (fp64, 16K x 128) -> bf16 bits ============
__global__ void k_xcast(const double* __restrict__ y, unsigned short* __restrict__ xb) {
    const size_t t = (size_t)blockIdx.x * 256 + threadIdx.x;   // chunk of 8
    const double* src = y + t * 8;
    unsigned short o[8];
    #pragma unroll
    for (int i = 0; i < 8; ++i) o[i] = f2bf((float)src[i]);
    *(int4*)&xb[t * 8] = *(int4*)o;
}

// ============ distance matrix GEMM, symmetric-triangle, all 16 batches ============
template<int C>
__global__ __launch_bounds__(256, 3) void k_dist(const float* __restrict__ xf,
                                                 const float* __restrict__ sqf,
                                                 float* __restrict__ D) {
    const int b = blockIdx.z;
    const float* xb = xf + (size_t)b * NN * C;
    int t = blockIdx.x;
    int ti = (int)((sqrtf(8.f * t + 1.f) - 1.f) * 0.5f);
    while (ti * (ti + 1) / 2 > t) --ti;
    while ((ti + 1) * (ti + 2) / 2 <= t) ++ti;
    const int tj = t - ti * (ti + 1) / 2;
    const int tx = threadIdx.x & 15, ty = threadIdx.x >> 4;
    const int row0 = ti * 64, col0 = tj * 64;
    float acc[4][4] = {};
    if constexpr (C == 3) {
        float ar[4][3], bc[4][3];
        #pragma unroll
        for (int i = 0; i < 4; ++i)
            #pragma unroll
            for (int c = 0; c < 3; ++c) {
                ar[i][c] = xb[(size_t)(row0 + ty * 4 + i) * 3 + c];
                bc[i][c] = xb[(size_t)(col0 + tx * 4 + i) * 3 + c];
            }
        #pragma unroll
        for (int i = 0; i < 4; ++i)
            #pragma unroll
            for (int j = 0; j < 4; ++j)
                acc[i][j] = ar[i][0]*bc[j][0] + ar[i][1]*bc[j][1] + ar[i][2]*bc[j][2];
    } else {
        __shared__ float As[32][65], Bs[32][65];
        for (int k0 = 0; k0 < C; k0 += 32) {
            for (int tt = threadIdx.x; tt < 512; tt += 256) {
                int r = tt >> 3, kq = (tt & 7) * 4;
                float4 va = *(const float4*)&xb[(size_t)(row0 + r) * C + k0 + kq];
                As[kq+0][r] = va.x; As[kq+1][r] = va.y; As[kq+2][r] = va.z; As[kq+3][r] = va.w;
                float4 vb = *(const float4*)&xb[(size_t)(col0 + r) * C + k0 + kq];
                Bs[kq+0][r] = vb.x; Bs[kq+1][r] = vb.y; Bs[kq+2][r] = vb.z; Bs[kq+3][r] = vb.w;
            }
            __syncthreads();
            #pragma unroll 4
            for (int kk = 0; kk < 32; ++kk) {
                float a[4], bb[4];
                #pragma unroll
                for (int i = 0; i < 4; ++i) { a[i] = As[kk][ty*4+i]; bb[i] = Bs[kk][tx*4+i]; }
                #pragma unroll
                for (int i = 0; i < 4; ++i)
                    #pragma unroll
                    for (int j = 0; j < 4; ++j)
                        acc[i][j] += a[i] * bb[j];
            }
            __syncthreads();
        }
    }
    float sr[4], sc[4];
    #pragma unroll
    for (int i = 0; i < 4; ++i) {
        sr[i] = sqf[b * NN + row0 + ty * 4 + i];
        sc[i] = sqf[b * NN + col0 + tx * 4 + i];
    }
    float* Dp = D + (size_t)b * NN * NN;
    #pragma unroll
    for (int i = 0; i < 4; ++i) {
        int r = row0 + ty * 4 + i;
        float4 st;
        float* e = &st.x;
        #pragma unroll
        for (int j = 0; j < 4; ++j) {
            float v = sr[i] + sc[j] - 2.f * acc[i][j];
            if (r == col0 + tx * 4 + j) v += 1e10f;
            e[j] = v;
        }
        *(float4*)&Dp[(size_t)r * NN + col0 + tx * 4] = st;
    }
    if (ti != tj) {
        #pragma unroll
        for (int j = 0; j < 4; ++j) {
            int c = col0 + tx * 4 + j;
            float4 st;
            st.x = sr[0] + sc[j] - 2.f * acc[0][j];
            st.y = sr[1] + sc[j] - 2.f * acc[1][j];
            st.z = sr[2] + sc[j] - 2.f * acc[2][j];
            st.w = sr[3] + sc[j] - 2.f * acc[3][j];
            *(float4*)&Dp[(size_t)c * NN + row0 + ty * 4] = st;
        }
    }
}

// ============ selection: packed-u32 cached-min top-MARGIN + fp64 re-rank ============
template<int C>
__global__ __launch_bounds__(256, 2) void k_select(const float* __restrict__ D,
                                                   const double* __restrict__ xd,
                                                   const double* __restrict__ sqd,
                                                   int* __restrict__ idx) {
    const int lane = threadIdx.x & 63, w = threadIdx.x >> 6;
    const int n = blockIdx.x * 4 + w;
    const int b = blockIdx.y;
    const float* Drow = D + ((size_t)b * NN + n) * NN;

    unsigned key[16];
    const float4* dv = (const float4*)(Drow + lane * 16);
    #pragma unroll
    for (int q = 0; q < 4; ++q) {
        float4 v = dv[q];
        key[q*4+0] = (fkey(v.x) & 0xFFFFFFF0u) | (unsigned)(q*4+0);
        key[q*4+1] = (fkey(v.y) & 0xFFFFFFF0u) | (unsigned)(q*4+1);
        key[q*4+2] = (fkey(v.z) & 0xFFFFFFF0u) | (unsigned)(q*4+2);
        key[q*4+3] = (fkey(v.w) & 0xFFFFFFF0u) | (unsigned)(q*4+3);
    }
    unsigned lmin = key[0];
    #pragma unroll
    for (int c = 1; c < 16; ++c) lmin = min(lmin, key[c]);

    int pm[MARGIN];
    int pickm = 0;
    #pragma unroll
    for (int it = 0; it < MARGIN; ++it) {
        unsigned gmin = lmin;
        #pragma unroll
        for (int off = 32; off > 0; off >>= 1)
            gmin = min(gmin, (unsigned)__shfl_xor((int)gmin, off, 64));
        unsigned long long msk = __ballot(lmin == gmin);
        int L = (int)__ffsll(msk) - 1;
        int m = L * 16 + (int)(gmin & 15u);
        pm[it] = m;
        if (lane == it) pickm = m;
        if (lane == L) {
            int jj = (int)(gmin & 15u);
            #pragma unroll
            for (int c = 0; c < 16; ++c) if (c == jj) key[c] = 0xFFFFFFFFu;
            lmin = key[0];
            #pragma unroll
            for (int c = 1; c < 16; ++c) lmin = min(lmin, key[c]);
        }
    }

    // ---- fp64 exact re-rank of the MARGIN candidates ----
    const double* xdb  = xd + (size_t)b * NN * C;
    const double* sqdb = sqd + b * NN;
    const double sqnD = sqdb[n];
    double qv0 = (lane < C) ? xdb[(size_t)n * C + lane] : 0.0;
    double qv1 = (C > 64) ? xdb[(size_t)n * C + lane + 64] : 0.0;
    double sqv = (lane < MARGIN) ? sqdb[pickm] : 0.0;
    double pv0[MARGIN], pv1[(C > 64) ? MARGIN : 1];
    #pragma unroll
    for (int j = 0; j < MARGIN; ++j) {
        pv0[j] = (lane < C) ? xdb[(size_t)pm[j] * C + lane] : 0.0;
        if (C > 64) pv1[j] = xdb[(size_t)pm[j] * C + lane + 64];
    }
    double myv = 1e300; int mym = 0x7FFFFFFF;
    #pragma unroll
    for (int j = 0; j < MARGIN; ++j) {
        double part = pv0[j] * qv0;
        if (C > 64) part += pv1[j] * qv1;
        #pragma unroll
        for (int off = 32; off > 0; off >>= 1) part += __shfl_xor(part, off, 64);
        if (lane == j) { myv = sqnD + sqv - 2.0 * part; mym = pm[j]; }
    }
    unsigned rank = 0;
    for (int i = 0; i < MARGIN; ++i) {
        double vi = __shfl(myv, i, 64);
        int    mi = __shfl(mym, i, 64);
        if (vi < myv || (vi == myv && mi < mym)) ++rank;
    }
    if (lane < MARGIN && rank < KK)
        idx[(size_t)(b * NN + n) * KK + rank] = mym;
}

// ============ UV GEMM fp64, 64-column chunk (L1-3) ============
template<int C>
__global__ void k_uv_d(const double* __restrict__ x, const float* __restrict__ W,
                       const float* __restrict__ bias,
                       double* __restrict__ U, double* __restrict__ V,
                       int Cout, int c0) {
    __shared__ double xt[16 * C];
    const int tid = threadIdx.x;
    const int col = tid & 63;
    const int gcol = c0 + col;
    const int r4 = tid >> 6;
    const int row0 = blockIdx.x * 16;
    for (int t = tid; t < 16 * C; t += 256) xt[t] = x[(size_t)row0 * C + t];
    __syncthreads();
    double u[4] = {0,0,0,0}, v[4] = {0,0,0,0};
    for (int c = 0; c < C; ++c) {
        double wt = (double)W[(size_t)c * Cout + gcol];
        double wd = (double)W[(size_t)(C + c) * Cout + gcol] - wt;
        #pragma unroll
        for (int rr = 0; rr < 4; ++rr) {
            double xv = xt[(r4 * 4 + rr) * C + c];
            u[rr] += xv * wt;
            v[rr] += xv * wd;
        }
    }
    double bb = (double)bias[gcol];
    #pragma unroll
    for (int rr = 0; rr < 4; ++rr) {
        size_t o = (size_t)(row0 + r4 * 4 + rr) * 64 + col;
        U[o] = u[rr] + bb;
        V[o] = v[rr];
    }
}

// ============ gather fp64 (L1-3): XCD-swizzled, barrier-free ============
__global__ __launch_bounds__(256, 4) void k_gath13(const int* __restrict__ idx,
                                                   double* __restrict__ U,
                                                   const double* __restrict__ V,
                                                   double* __restrict__ Hmin,
                                                   double* __restrict__ PS,
                                                   double* __restrict__ PQ) {
    const int lane = threadIdx.x & 63, w = threadIdx.x >> 6;
    int batch, s;
    xcd_decode(blockIdx.x, batch, s);
    const int base = (batch << 10) + (s << 4);
    const int b = batch;
    const int wid = blockIdx.x * 4 + w;
    const int gn0 = base + w * 4;
    double accs = 0.0, accq = 0.0;
    for (int r = 0; r < 4; ++r) {
        int gn = gn0 + r;
        int my = (lane < KK) ? idx[(size_t)gn * KK + lane] : 0;
        double u = U[(size_t)gn * 64 + lane];
        double vmax = -1e300, vmin = 1e300, vs = 0.0, vss = 0.0;
        #pragma unroll
        for (int j = 0; j < KK; ++j) {
            int m = __shfl(my, j, 64);
            double vv = V[(size_t)((b << 10) + m) * 64 + lane];
            vmax = fmax(vmax, vv);
            vmin = fmin(vmin, vv);
            vs  += vv;
            vss += vv * vv;
        }
        accs += (double)KK * u + vs;
        accq += (double)KK * u * u + 2.0 * u * vs + vss;
        U[(size_t)gn * 64 + lane]    = u + vmax;
        Hmin[(size_t)gn * 64 + lane] = u + vmin;
    }
    PS[(size_t)wid * 64 + lane] = accs;
    PQ[(size_t)wid * 64 + lane] = accq;
}

// ============ BN reduce stage 1 (L1-3) ============
template<int CS>
__global__ __launch_bounds__(256) void k_bnred1(const double* __restrict__ PS,
                                                const double* __restrict__ PQ,
                                                double* __restrict__ PS2,
                                                double* __restrict__ PQ2) {
    const int NG = 256 / CS;
    const int tid = threadIdx.x, ch = tid & (CS - 1), grp = tid / CS;
    const int r0 = blockIdx.x * 64;
    double s = 0.0, q = 0.0;
    for (int r = grp; r < 64; r += NG) {
        s += PS[(size_t)(r0 + r) * CS + ch];
        q += PQ[(size_t)(r0 + r) * CS + ch];
    }
    __shared__ double rs[256], rq[256];
    rs[tid] = s; rq[tid] = q;
    __syncthreads();
    if (grp == 0) {
        #pragma unroll
        for (int g = 1; g < NG; ++g) { s += rs[g * CS + ch]; q += rq[g * CS + ch]; }
        PS2[(size_t)blockIdx.x * CS + ch] = s;
        PQ2[(size_t)blockIdx.x * CS + ch] = q;
    }
}

// ============ BN finalize stage 2 (fp64 S/T, L1-3) ============
template<int CS>
__global__ __launch_bounds__(256) void k_bnfin2_d(const double* __restrict__ PS2,
                                                  const double* __restrict__ PQ2,
                                                  const float* __restrict__ g,
                                                  const float* __restrict__ be,
                                                  double* __restrict__ S,
                                                  double* __restrict__ T,
                                                  int c0, int nrows) {
    const int NG = 256 / CS;
    const int tid = threadIdx.x, ch = tid & (CS - 1), grp = tid / CS;
    double s = 0.0, q = 0.0;
    for (int r = grp; r < nrows; r += NG) {
        s += PS2[(size_t)r * CS + ch];
        q += PQ2[(size_t)r * CS + ch];
    }
    __shared__ double rs[256], rq[256];
    rs[tid] = s; rq[tid] = q;
    __syncthreads();
    if (grp == 0) {
        #pragma unroll
        for (int gg = 1; gg < NG; ++gg) { s += rs[gg * CS + ch]; q += rq[gg * CS + ch]; }
        const double M = (double)BN * (double)KK;
        double mean = s / M;
        double var  = q / M - mean * mean;
        if (var < 0.0) var = 0.0;
        double sc = (double)g[c0 + ch] / sqrt(var + 1e-5);
        S[c0 + ch] = sc;
        T[c0 + ch] = (double)be[c0 + ch] - mean * sc;
    }
}

// ============ apply fp64 chunk (L3) ============
__global__ void k_apply_d(const double* __restrict__ Hmax, const double* __restrict__ Hmin,
                          const double* __restrict__ S, const double* __restrict__ T,
                          double* __restrict__ y, int Cout, int c0) {
    const int gn = blockIdx.x, tid = threadIdx.x;
    double s = S[c0 + tid], t = T[c0 + tid];
    double h = (s >= 0.0) ? Hmax[(size_t)gn * 64 + tid] : Hmin[(size_t)gn * 64 + tid];
    y[(size_t)gn * Cout + c0 + tid] = fmax(s * h + t, 0.0);
}

// ============ fused apply+prep (L1/L2), wave per row ============
__global__ void k_applyprep_d(const double* __restrict__ Hmax, const double* __restrict__ Hmin,
                              const double* __restrict__ S, const double* __restrict__ T,
                              double* __restrict__ y, float* __restrict__ yf,
                              double* __restrict__ sqd, float* __restrict__ sqf) {
    const int gn = blockIdx.x, lane = threadIdx.x;   // blockDim = 64
    double s = S[lane], t = T[lane];
    double h = (s >= 0.0) ? Hmax[(size_t)gn * 64 + lane] : Hmin[(size_t)gn * 64 + lane];
    double val = fmax(s * h + t, 0.0);
    y[(size_t)gn * 64 + lane] = val;
    yf[(size_t)gn * 64 + lane] = (float)val;
    double ss = val * val;
    #pragma unroll
    for (int off = 32; off > 0; off >>= 1) ss += __shfl_xor(ss, off, 64);
    if (lane == 0) { sqd[gn] = ss; sqf[gn] = (float)ss; }
}

// ============ layer-4 UV GEMM via bf16 MFMA ============
__global__ __launch_bounds__(256, 2) void k_uv_mfma(const unsigned short* __restrict__ Xbf,
                                                    const unsigned short* __restrict__ Wtb,
                                                    const unsigned short* __restrict__ Wdb,
                                                    const float* __restrict__ bias,
                                                    float* __restrict__ U,
                                                    float* __restrict__ V) {
    __shared__ unsigned short As[64 * 136];
    __shared__ unsigned short Bs[64 * 136];
    const int tid = threadIdx.x, lane = tid & 63, w = tid >> 6;
    const int col0 = blockIdx.x * 64;      // 0..2047
    const int row0 = blockIdx.y * 64;
    const unsigned short* Bsrc = (col0 < 1024) ? (Wtb + (size_t)col0 * 128)
                                               : (Wdb + (size_t)(col0 - 1024) * 128);
    #pragma unroll
    for (int i = 0; i < 4; ++i) {
        int c = tid + i * 256;
        int r = c >> 4, part = c & 15;
        *(int4*)&As[r * 136 + part * 8] =
            *(const int4*)&Xbf[(size_t)(row0 + r) * 128 + part * 8];
        *(int4*)&Bs[r * 136 + part * 8] =
            *(const int4*)&Bsrc[(size_t)r * 128 + part * 8];
    }
    __syncthreads();
    const int quad = lane >> 4, m16 = lane & 15;
    f32x4 acc[4] = {};
    #pragma unroll
    for (int kk = 0; kk < 4; ++kk) {
        bf16x8v af = *(const bf16x8v*)&As[(w * 16 + m16) * 136 + kk * 32 + quad * 8];
        #pragma unroll
        for (int t = 0; t < 4; ++t) {
            bf16x8v bfr = *(const bf16x8v*)&Bs[(t * 16 + m16) * 136 + kk * 32 + quad * 8];
            acc[t] = __builtin_amdgcn_mfma_f32_16x16x32_bf16(af, bfr, acc[t], 0, 0, 0);
        }
    }
    const int rbase = row0 + w * 16 + quad * 4;
    if (col0 < 1024) {
        #pragma unroll
        for (int t = 0; t < 4; ++t) {
            int col = col0 + t * 16 + m16;
            float bb = bias[col];
            #pragma unroll
            for (int r = 0; r < 4; ++r)
                U[(size_t)(rbase + r) * 1024 + col] = acc[t][r] + bb;
        }
    } else {
        #pragma unroll
        for (int t = 0; t < 4; ++t) {
            int col = col0 - 1024 + t * 16 + m16;
            #pragma unroll
            for (int r = 0; r < 4; ++r)
                V[(size_t)(rbase + r) * 1024 + col] = acc[t][r];
        }
    }
}

// ============ layer-4 gather v3: one batch per XCD resident set, nt U loads, ============
// REGULAR PS/PQ stores (nt stores caused 4x write amplification in round 16).
__global__ __launch_bounds__(256, 4) void k_gath4(const int* __restrict__ idx,
                                                  const float* __restrict__ U,
                                                  const float* __restrict__ V,
                                                  unsigned* __restrict__ Zmax,
                                                  unsigned* __restrict__ Zmin,
                                                  double* __restrict__ PS,
                                                  double* __restrict__ PQ) {
    const int tid = threadIdx.x, lane = tid & 63;
    const int p = blockIdx.x;
    const int batch = (p & 7) + ((p >> 10) << 3);
    const int s = (p >> 3) & 127;
    const int gn0 = (batch << 10) + (s << 3);   // 8 rows per block
    const int b = batch;
    const int c4 = tid * 4;
    double accs[4] = {0,0,0,0}, accq[4] = {0,0,0,0};
    float rmax[4] = {-3e38f,-3e38f,-3e38f,-3e38f};
    float rmin[4] = { 3e38f, 3e38f, 3e38f, 3e38f};
    for (int r = 0; r < 8; ++r) {
        int gn = gn0 + r;
        int my = (lane < KK) ? idx[(size_t)gn * KK + lane] : 0;
        f32x4 u4 = __builtin_nontemporal_load((const f32x4*)&U[(size_t)gn * 1024 + c4]);
        float um[4] = {u4[0], u4[1], u4[2], u4[3]};
        float vmax[4] = {-3e38f,-3e38f,-3e38f,-3e38f};
        float vmin[4] = { 3e38f, 3e38f, 3e38f, 3e38f};
        float vs[4] = {0,0,0,0}, vss[4] = {0,0,0,0};
        #pragma unroll
        for (int j = 0; j < KK; ++j) {
            int m = __shfl(my, j, 64);
            float4 vv4 = *(const float4*)&V[(size_t)((b << 10) + m) * 1024 + c4];
            float vv[4] = {vv4.x, vv4.y, vv4.z, vv4.w};
            #pragma unroll
            for (int e = 0; e < 4; ++e) {
                vmax[e] = fmaxf(vmax[e], vv[e]);
                vmin[e] = fminf(vmin[e], vv[e]);
                vs[e]  += vv[e];
                vss[e] += vv[e] * vv[e];
            }
        }
        #pragma unroll
        for (int e = 0; e < 4; ++e) {
            accs[e] += (double)((float)KK * um[e] + vs[e]);
            accq[e] += (double)((float)KK * um[e] * um[e] + 2.f * um[e] * vs[e] + vss[e]);
            rmax[e] = fmaxf(rmax[e], um[e] + vmax[e]);
            rmin[e] = fminf(rmin[e], um[e] + vmin[e]);
        }
    }
    #pragma unroll
    for (int e = 0; e < 4; ++e) {
        PS[(size_t)p * 1024 + c4 + e] = accs[e];
        PQ[(size_t)p * 1024 + c4 + e] = accq[e];
        atomicMax(&Zmax[b * 1024 + c4 + e], fkey(rmax[e]));
        atomicMin(&Zmin[b * 1024 + c4 + e], fkey(rmin[e]));
    }
}

// ============ L4 BN reduce: 2048 partial rows x 1024 ch ============
__global__ __launch_bounds__(256) void k_bnred1_L4(const double* __restrict__ PS,
                                                   const double* __restrict__ PQ,
                                                   double* __restrict__ PS2,
                                                   double* __restrict__ PQ2) {
    const int ch = (blockIdx.x & 3) * 256 + threadIdx.x;
    const int r0 = (blockIdx.x >> 2) * 64;
    double s = 0.0, q = 0.0;
    for (int r = 0; r < 64; ++r) {
        s += PS[(size_t)(r0 + r) * 1024 + ch];
        q += PQ[(size_t)(r0 + r) * 1024 + ch];
    }
    PS2[(size_t)(blockIdx.x >> 2) * 1024 + ch] = s;
    PQ2[(size_t)(blockIdx.x >> 2) * 1024 + ch] = q;
}

__global__ __launch_bounds__(256) void k_bnfin_L4(const double* __restrict__ PS2,
                                                  const double* __restrict__ PQ2,
                                                  const float* __restrict__ g,
                                                  const float* __restrict__ be,
                                                  float* __restrict__ S,
                                                  float* __restrict__ T) {
    const int ch = blockIdx.x * 256 + threadIdx.x;
    double s = 0.0, q = 0.0;
    for (int r = 0; r < 32; ++r) {
        s += PS2[(size_t)r * 1024 + ch];
        q += PQ2[(size_t)r * 1024 + ch];
    }
    const double M = (double)BN * (double)KK;
    double mean = s / M;
    double var  = q / M - mean * mean;
    if (var < 0.0) var = 0.0;
    float sc = (float)((double)g[ch] / sqrt(var + 1e-5));
    S[ch] = sc;
    T[ch] = (float)((double)be[ch] - mean * (double)sc);
}

// ============ layer-4 finalize ============
__global__ void k_zfin(const unsigned* __restrict__ Zmax, const unsigned* __restrict__ Zmin,
                       const float* __restrict__ S, const float* __restrict__ T,
                       float* __restrict__ z) {
    const int b = blockIdx.y;
    const int c = blockIdx.x * 64 + threadIdx.x;
    float s = S[c], t = T[c];
    float e = (s >= 0.f) ? funkey(Zmax[b * 1024 + c]) : funkey(Zmin[b * 1024 + c]);
    z[(size_t)b * 1024 + c] = fmaxf(s * e + t, 0.f);
}

// ============ FC head ============
__global__ __launch_bounds__(256) void k_fc1(const float* __restrict__ z,
                                             const float* __restrict__ Wc1,
                                             const float* __restrict__ bc1,
                                             float* __restrict__ a1) {
    __shared__ float zs[1024];
    __shared__ float red[256];
    const int b = blockIdx.y, j0 = blockIdx.x * 64;
    const int tid = threadIdx.x, tj = tid & 63, seg = tid >> 6;
    for (int t = tid; t < 1024; t += 256) zs[t] = z[b * 1024 + t];
    __syncthreads();
    float acc = 0.f;
    #pragma unroll 8
    for (int c = seg * 256; c < seg * 256 + 256; ++c)
        acc += zs[c] * Wc1[(size_t)c * 512 + j0 + tj];
    red[tid] = acc;
    __syncthreads();
    if (seg == 0) {
        float s = red[tj] + red[64 + tj] + red[128 + tj] + red[192 + tj] + bc1[j0 + tj];
        a1[b * 512 + j0 + tj] = fmaxf(s, 0.f);
    }
}

__global__ void k_fc2(const float* __restrict__ a1, const float* __restrict__ Wc2,
                      const float* __restrict__ bc2, float* __restrict__ out) {
    const int j = blockIdx.x, b = blockIdx.y, lane = threadIdx.x;
    float acc = 0.f;
    #pragma unroll
    for (int c8 = 0; c8 < 8; ++c8) {
        int c = c8 * 64 + lane;
        acc += a1[b * 512 + c] * Wc2[(size_t)c * 40 + j];
    }
    #pragma unroll
    for (int off = 32; off > 0; off >>= 1) acc += __shfl_xor(acc, off, 64);
    if (lane == 0) out[b * 40 + j] = acc + bc2[j];
}

extern "C" void kernel_launch(void* const* d_in, const int* in_sizes, int n_in,
                              void* d_out, int out_size, void* d_ws, size_t ws_size,
                              hipStream_t stream) {
    const float* pos = (const float*)d_in[0];
    const float* Wc1 = (const float*)d_in[17];
    const float* bc1 = (const float*)d_in[18];
    const float* Wc2 = (const float*)d_in[19];
    const float* bc2 = (const float*)d_in[20];

    char* p = (char*)d_ws;
    auto alloc = [&](size_t bytes) -> void* {
        void* r = (void*)p;
        p += (bytes + 255) & ~(size_t)255;
        return r;
    };
    float*    Dm   = (float*) alloc((size_t)BB * NN * NN * 4);   // 64 MB; aliased as Ufull in L4
    float*    Vfull= (float*) alloc((size_t)BN * 1024 * 4);      // 64 MB (L4 V)
    void*     bufA = alloc((size_t)BN * 64 * 8);    // Ud (L1-3)
    void*     bufB = alloc((size_t)BN * 64 * 8);    // Vd
    void*     bufC = alloc((size_t)BN * 64 * 8);    // Hmin (L1-3) / Ybf fp32 (L4)
    double*   Ya   = (double*)alloc((size_t)BN * 64 * 8);
    double*   Yb   = (double*)alloc((size_t)BN * 128 * 8);
    float*    Yaf  = (float*) alloc((size_t)BN * 64 * 4);
    double*   Xd   = (double*)alloc((size_t)BN * 3 * 8);
    double*   SQd  = (double*)alloc((size_t)BN * 8);
    float*    SQf  = (float*) alloc((size_t)BN * 4);
    int*      IDX  = (int*)   alloc((size_t)BN * KK * 4);
    unsigned short* Xbf = (unsigned short*)alloc((size_t)BN * 128 * 2);  // 4 MB bf16 X
    unsigned short* Wtb = (unsigned short*)alloc((size_t)1024 * 128 * 2);
    unsigned short* Wdb = (unsigned short*)alloc((size_t)1024 * 128 * 2);
    double*   PARTS= (double*)alloc((size_t)4096 * 64 * 8);
    double*   PARTQ= (double*)alloc((size_t)4096 * 64 * 8);
    double*   PS2  = (double*)alloc((size_t)64 * 128 * 8);
    double*   PQ2  = (double*)alloc((size_t)64 * 128 * 8);
    double*   PL4S = (double*)alloc((size_t)2048 * 1024 * 8);  // 16 MB (2048 partial rows)
    double*   PL4Q = (double*)alloc((size_t)2048 * 1024 * 8);
    double*   PL4S2= (double*)alloc((size_t)32 * 1024 * 8);
    double*   PL4Q2= (double*)alloc((size_t)32 * 1024 * 8);
    double*   Sd   = (double*)alloc((size_t)128 * 8);
    double*   Td   = (double*)alloc((size_t)128 * 8);
    float*    Sf   = (float*) alloc((size_t)1024 * 4);
    float*    Tf   = (float*) alloc((size_t)1024 * 4);
    unsigned* Zmax = (unsigned*)alloc((size_t)BB * 1024 * 4);
    unsigned* Zmin = (unsigned*)alloc((size_t)BB * 1024 * 4);
    float*    Z    = (float*) alloc((size_t)BB * 1024 * 4);
    float*    A1   = (float*) alloc((size_t)BB * 512 * 4);
    // total ~= 239 MB (ws = 256 MiB)

    double* Ud = (double*)bufA; double* Vd = (double*)bufB; double* Hd = (double*)bufC;
    float*  Ybf = (float*)bufC;
    float*  Ufull = Dm;    // D dead after L4 select; reuse as full-width U

    hipMemsetAsync(Zmax, 0x00, (size_t)BB * 1024 * 4, stream);
    hipMemsetAsync(Zmin, 0xFF, (size_t)BB * 1024 * 4, stream);

    k_cast3<<<(BN + 255) / 256, 256, 0, stream>>>(pos, Xd, SQd, SQf);
    k_wprep<<<dim3(16, 4), 256, 0, stream>>>((const float*)d_in[13], Wtb, Wdb);

    // ---- Layer 1: C=3 -> 64 ----
    {
        const float* W = (const float*)d_in[1], *bs = (const float*)d_in[2];
        const float* g = (const float*)d_in[3], *be = (const float*)d_in[4];
        k_dist<3><<<dim3(136, 1, BB), 256, 0, stream>>>(pos, SQf, Dm);
        k_select<3><<<dim3(NN / 4, BB), 256, 0, stream>>>(Dm, Xd, SQd, IDX);
        k_uv_d<3><<<BN / 16, 256, 0, stream>>>(Xd, W, bs, Ud, Vd, 64, 0);
        k_gath13<<<BN / 16, 256, 0, stream>>>(IDX, Ud, Vd, Hd, PARTS, PARTQ);
        k_bnred1<64><<<64, 256, 0, stream>>>(PARTS, PARTQ, PS2, PQ2);
        k_bnfin2_d<64><<<1, 256, 0, stream>>>(PS2, PQ2, g, be, Sd, Td, 0, 64);
        k_applyprep_d<<<BN, 64, 0, stream>>>(Ud, Hd, Sd, Td, Ya, Yaf, SQd, SQf);
    }
    // ---- Layer 2: C=64 -> 64 ----
    {
        const float* W = (const float*)d_in[5], *bs = (const float*)d_in[6];
        const float* g = (const float*)d_in[7], *be = (const float*)d_in[8];
        k_dist<64><<<dim3(136, 1, BB), 256, 0, stream>>>(Yaf, SQf, Dm);
        k_select<64><<<dim3(NN / 4, BB), 256, 0, stream>>>(Dm, Ya, SQd, IDX);
        k_uv_d<64><<<BN / 16, 256, 0, stream>>>(Ya, W, bs, Ud, Vd, 64, 0);
        k_gath13<<<BN / 16, 256, 0, stream>>>(IDX, Ud, Vd, Hd, PARTS, PARTQ);
        k_bnred1<64><<<64, 256, 0, stream>>>(PARTS, PARTQ, PS2, PQ2);
        k_bnfin2_d<64><<<1, 256, 0, stream>>>(PS2, PQ2, g, be, Sd, Td, 0, 64);
        k_applyprep_d<<<BN, 64, 0, stream>>>(Ud, Hd, Sd, Td, Ya, Yaf, SQd, SQf);
    }
    // ---- Layer 3: C=64 -> 128, two 64-col chunks, Ya -> Yb ----
    {
        const float* W = (const float*)d_in[9], *bs = (const float*)d_in[10];
        const float* g = (const float*)d_in[11], *be = (const float*)d_in[12];
        k_dist<64><<<dim3(136, 1, BB), 256, 0, stream>>>(Yaf, SQf, Dm);
        k_select<64><<<dim3(NN / 4, BB), 256, 0, stream>>>(Dm, Ya, SQd, IDX);
        for (int cc = 0; cc < 2; ++cc) {
            const int c0 = cc * 64;
            k_uv_d<64><<<BN / 16, 256, 0, stream>>>(Ya, W, bs, Ud, Vd, 128, c0);
            k_gath13<<<BN / 16, 256, 0, stream>>>(IDX, Ud, Vd, Hd, PARTS, PARTQ);
            k_bnred1<64><<<64, 256, 0, stream>>>(PARTS, PARTQ, PS2, PQ2);
            k_bnfin2_d<64><<<1, 256, 0, stream>>>(PS2, PQ2, g, be, Sd, Td, c0, 64);
            k_apply_d<<<BN, 64, 0, stream>>>(Ud, Hd, Sd, Td, Yb, 128, c0);
        }
        k_prep<<<BN / 4, 256, 0, stream>>>(Yb, Ybf, SQd, SQf, 128);   // Ybf = bufC
    }
    // ---- Layer 4: C=128 -> 1024, bf16 MFMA UV + single-pass gather ----
    {
        const float* bs = (const float*)d_in[14];
        const float* g = (const float*)d_in[15], *be = (const float*)d_in[16];
        k_dist<128><<<dim3(136, 1, BB), 256, 0, stream>>>(Ybf, SQf, Dm);
        k_select<128><<<dim3(NN / 4, BB), 256, 0, stream>>>(Dm, Yb, SQd, IDX);
        k_xcast<<<BN * 128 / 2048, 256, 0, stream>>>(Yb, Xbf);
        // Dm is now dead -> Ufull aliases it
        k_uv_mfma<<<dim3(32, BN / 64), 256, 0, stream>>>(Xbf, Wtb, Wdb, bs, Ufull, Vfull);
        k_gath4<<<2048, 256, 0, stream>>>(IDX, Ufull, Vfull, Zmax, Zmin, PL4S, PL4Q);
        k_bnred1_L4<<<128, 256, 0, stream>>>(PL4S, PL4Q, PL4S2, PL4Q2);
        k_bnfin_L4<<<4, 256, 0, stream>>>(PL4S2, PL4Q2, g, be, Sf, Tf);
        k_zfin<<<dim3(16, BB), 64, 0, stream>>>(Zmax, Zmin, Sf, Tf, Z);
    }

    k_fc1<<<dim3(8, BB), 256, 0, stream>>>(Z, Wc1, bc1, A1);
    k_fc2<<<dim3(40, BB), 64, 0, stream>>>(A1, Wc2, bc2, (float*)d_out);
}

// Round 18
// 959.211 us; speedup vs baseline: 1.0829x; 1.0829x over previous
//
#include <hip/hip_runtime.h>
#include <hip/hip_bf16.h>

#define BB 16
#define NN 1024
#define BN (BB*NN)
#define KK 20
#define MARGIN 25   // fp32 prefilter width (>= KK + safety)

typedef short bf16x8v __attribute__((ext_vector_type(8)));
typedef float f32x4   __attribute__((ext_vector_type(4)));
typedef unsigned short u16x4 __attribute__((ext_vector_type(4)));

// monotone float <-> uint key for atomic max/min (handles negatives)
__device__ inline unsigned fkey(float x) {
    unsigned b = __float_as_uint(x);
    return (b & 0x80000000u) ? ~b : (b | 0x80000000u);
}
__device__ inline float funkey(unsigned k) {
    unsigned b = (k & 0x80000000u) ? (k ^ 0x80000000u) : ~k;
    return __uint_as_float(b);
}
// fp32 -> bf16 bits, round-to-nearest-even
__device__ inline unsigned short f2bf(float x) {
    unsigned u = __float_as_uint(x);
    return (unsigned short)((u + 0x7FFFu + ((u >> 16) & 1u)) >> 16);
}
__device__ inline float bf2f(unsigned short u) {
    return __uint_as_float((unsigned)u << 16);
}

// XCD-aware swizzle (L1-3 gather): 1024 blocks = 16 batches x 64 subs.
__device__ inline void xcd_decode(int p, int& batch, int& s) {
    int xcd = p & 7, rem = p >> 3;
    s = rem & 63;
    batch = xcd + ((rem >> 6) << 3);
}

// ============ cast pos -> double + row sqnorm (fp64 + fp32) ============
__global__ void k_cast3(const float* __restrict__ pos, double* __restrict__ xd,
                        double* __restrict__ sqd, float* __restrict__ sqf) {
    int gn = blockIdx.x * blockDim.x + threadIdx.x;
    if (gn >= BN) return;
    double s = 0.0;
    #pragma unroll
    for (int c = 0; c < 3; ++c) {
        double v = (double)pos[gn * 3 + c];
        xd[gn * 3 + c] = v;
        s += v * v;
    }
    sqd[gn] = s;
    sqf[gn] = (float)s;
}

// ============ prep: fp64 y -> fp32 copy + sqnorms (fp64 + fp32) ============
__global__ void k_prep(const double* __restrict__ y, float* __restrict__ yf,
                       double* __restrict__ sqd, float* __restrict__ sqf, int C) {
    const int row = blockIdx.x * 4 + (threadIdx.x >> 6);
    const int lane = threadIdx.x & 63;
    const double* yr = y + (size_t)row * C;
    float* yfr = yf + (size_t)row * C;
    double s = 0.0;
    for (int c = lane; c < C; c += 64) {
        double v = yr[c];
        s += v * v;
        yfr[c] = (float)v;
    }
    #pragma unroll
    for (int off = 32; off > 0; off >>= 1) s += __shfl_xor(s, off, 64);
    if (lane == 0) { sqd[row] = s; sqf[row] = (float)s; }
}

// ============ W4 prep: transpose + bf16 + diff. W(256x1024) -> Wtb/Wdb [1024][128] ============
__global__ __launch_bounds__(256) void k_wprep(const float* __restrict__ W,
                                               unsigned short* __restrict__ Wtb,
                                               unsigned short* __restrict__ Wdb) {
    __shared__ float Lt[32][65], Ld[32][65];
    const int n0 = blockIdx.x * 64, k0 = blockIdx.y * 32;
    const int tid = threadIdx.x;
    {
        const int nn = tid & 63, kg = tid >> 6;
        #pragma unroll
        for (int i = 0; i < 8; ++i) {
            int kk = kg * 8 + i;
            float wt = W[(size_t)(k0 + kk) * 1024 + n0 + nn];
            float wb = W[(size_t)(128 + k0 + kk) * 1024 + n0 + nn];
            Lt[kk][nn] = wt;
            Ld[kk][nn] = wb - wt;
        }
    }
    __syncthreads();
    {
        const int kk = tid & 31, ng = tid >> 5;
        #pragma unroll
        for (int i = 0; i < 8; ++i) {
            int nl = ng + i * 8;
            Wtb[(size_t)(n0 + nl) * 128 + k0 + kk] = f2bf(Lt[kk][nl]);
            Wdb[(size_t)(n0 + nl) * 128 + k0 + kk] = f2bf(Ld[kk][nl]);
        }
    }
}

// ============ Yb (fp64, 16K x 128) -> bf16 bits ============
__global__ void k_xcast(const double* __restrict__ y, unsigned short* __restrict__ xb) {
    const size_t t = (size_t)blockIdx.x * 256 + threadIdx.x;   // chunk of 8
    const double* src = y + t * 8;
    unsigned short o[8];
    #pragma unroll
    for (int i = 0; i < 8; ++i) o[i] = f2bf((float)src[i]);
    *(int4*)&xb[t * 8] = *(int4*)o;
}

// ============ distance matrix GEMM, symmetric-triangle, all 16 batches ============
template<int C>
__global__ __launch_bounds__(256, 3) void k_dist(const float* __restrict__ xf,
                                                 const float* __restrict__ sqf,
                                                 float* __restrict__ D) {
    const int b = blockIdx.z;
    const float* xb = xf + (size_t)b * NN * C;
    int t = blockIdx.x;
    int ti = (int)((sqrtf(8.f * t + 1.f) - 1.f) * 0.5f);
    while (ti * (ti + 1) / 2 > t) --ti;
    while ((ti + 1) * (ti + 2) / 2 <= t) ++ti;
    const int tj = t - ti * (ti + 1) / 2;
    const int tx = threadIdx.x & 15, ty = threadIdx.x >> 4;
    const int row0 = ti * 64, col0 = tj * 64;
    float acc[4][4] = {};
    if constexpr (C == 3) {
        float ar[4][3], bc[4][3];
        #pragma unroll
        for (int i = 0; i < 4; ++i)
            #pragma unroll
            for (int c = 0; c < 3; ++c) {
                ar[i][c] = xb[(size_t)(row0 + ty * 4 + i) * 3 + c];
                bc[i][c] = xb[(size_t)(col0 + tx * 4 + i) * 3 + c];
            }
        #pragma unroll
        for (int i = 0; i < 4; ++i)
            #pragma unroll
            for (int j = 0; j < 4; ++j)
                acc[i][j] = ar[i][0]*bc[j][0] + ar[i][1]*bc[j][1] + ar[i][2]*bc[j][2];
    } else {
        __shared__ float As[32][65], Bs[32][65];
        for (int k0 = 0; k0 < C; k0 += 32) {
            for (int tt = threadIdx.x; tt < 512; tt += 256) {
                int r = tt >> 3, kq = (tt & 7) * 4;
                float4 va = *(const float4*)&xb[(size_t)(row0 + r) * C + k0 + kq];
                As[kq+0][r] = va.x; As[kq+1][r] = va.y; As[kq+2][r] = va.z; As[kq+3][r] = va.w;
                float4 vb = *(const float4*)&xb[(size_t)(col0 + r) * C + k0 + kq];
                Bs[kq+0][r] = vb.x; Bs[kq+1][r] = vb.y; Bs[kq+2][r] = vb.z; Bs[kq+3][r] = vb.w;
            }
            __syncthreads();
            #pragma unroll 4
            for (int kk = 0; kk < 32; ++kk) {
                float a[4], bb[4];
                #pragma unroll
                for (int i = 0; i < 4; ++i) { a[i] = As[kk][ty*4+i]; bb[i] = Bs[kk][tx*4+i]; }
                #pragma unroll
                for (int i = 0; i < 4; ++i)
                    #pragma unroll
                    for (int j = 0; j < 4; ++j)
                        acc[i][j] += a[i] * bb[j];
            }
            __syncthreads();
        }
    }
    float sr[4], sc[4];
    #pragma unroll
    for (int i = 0; i < 4; ++i) {
        sr[i] = sqf[b * NN + row0 + ty * 4 + i];
        sc[i] = sqf[b * NN + col0 + tx * 4 + i];
    }
    float* Dp = D + (size_t)b * NN * NN;
    #pragma unroll
    for (int i = 0; i < 4; ++i) {
        int r = row0 + ty * 4 + i;
        float4 st;
        float* e = &st.x;
        #pragma unroll
        for (int j = 0; j < 4; ++j) {
            float v = sr[i] + sc[j] - 2.f * acc[i][j];
            if (r == col0 + tx * 4 + j) v += 1e10f;
            e[j] = v;
        }
        *(float4*)&Dp[(size_t)r * NN + col0 + tx * 4] = st;
    }
    if (ti != tj) {
        #pragma unroll
        for (int j = 0; j < 4; ++j) {
            int c = col0 + tx * 4 + j;
            float4 st;
            st.x = sr[0] + sc[j] - 2.f * acc[0][j];
            st.y = sr[1] + sc[j] - 2.f * acc[1][j];
            st.z = sr[2] + sc[j] - 2.f * acc[2][j];
            st.w = sr[3] + sc[j] - 2.f * acc[3][j];
            *(float4*)&Dp[(size_t)c * NN + row0 + ty * 4] = st;
        }
    }
}

// ============ selection: packed-u32 cached-min top-MARGIN + fp64 re-rank ============
template<int C>
__global__ __launch_bounds__(256, 2) void k_select(const float* __restrict__ D,
                                                   const double* __restrict__ xd,
                                                   const double* __restrict__ sqd,
                                                   int* __restrict__ idx) {
    const int lane = threadIdx.x & 63, w = threadIdx.x >> 6;
    const int n = blockIdx.x * 4 + w;
    const int b = blockIdx.y;
    const float* Drow = D + ((size_t)b * NN + n) * NN;

    unsigned key[16];
    const float4* dv = (const float4*)(Drow + lane * 16);
    #pragma unroll
    for (int q = 0; q < 4; ++q) {
        float4 v = dv[q];
        key[q*4+0] = (fkey(v.x) & 0xFFFFFFF0u) | (unsigned)(q*4+0);
        key[q*4+1] = (fkey(v.y) & 0xFFFFFFF0u) | (unsigned)(q*4+1);
        key[q*4+2] = (fkey(v.z) & 0xFFFFFFF0u) | (unsigned)(q*4+2);
        key[q*4+3] = (fkey(v.w) & 0xFFFFFFF0u) | (unsigned)(q*4+3);
    }
    unsigned lmin = key[0];
    #pragma unroll
    for (int c = 1; c < 16; ++c) lmin = min(lmin, key[c]);

    int pm[MARGIN];
    int pickm = 0;
    #pragma unroll
    for (int it = 0; it < MARGIN; ++it) {
        unsigned gmin = lmin;
        #pragma unroll
        for (int off = 32; off > 0; off >>= 1)
            gmin = min(gmin, (unsigned)__shfl_xor((int)gmin, off, 64));
        unsigned long long msk = __ballot(lmin == gmin);
        int L = (int)__ffsll(msk) - 1;
        int m = L * 16 + (int)(gmin & 15u);
        pm[it] = m;
        if (lane == it) pickm = m;
        if (lane == L) {
            int jj = (int)(gmin & 15u);
            #pragma unroll
            for (int c = 0; c < 16; ++c) if (c == jj) key[c] = 0xFFFFFFFFu;
            lmin = key[0];
            #pragma unroll
            for (int c = 1; c < 16; ++c) lmin = min(lmin, key[c]);
        }
    }

    // ---- fp64 exact re-rank of the MARGIN candidates ----
    const double* xdb  = xd + (size_t)b * NN * C;
    const double* sqdb = sqd + b * NN;
    const double sqnD = sqdb[n];
    double qv0 = (lane < C) ? xdb[(size_t)n * C + lane] : 0.0;
    double qv1 = (C > 64) ? xdb[(size_t)n * C + lane + 64] : 0.0;
    double sqv = (lane < MARGIN) ? sqdb[pickm] : 0.0;
    double pv0[MARGIN], pv1[(C > 64) ? MARGIN : 1];
    #pragma unroll
    for (int j = 0; j < MARGIN; ++j) {
        pv0[j] = (lane < C) ? xdb[(size_t)pm[j] * C + lane] : 0.0;
        if (C > 64) pv1[j] = xdb[(size_t)pm[j] * C + lane + 64];
    }
    double myv = 1e300; int mym = 0x7FFFFFFF;
    #pragma unroll
    for (int j = 0; j < MARGIN; ++j) {
        double part = pv0[j] * qv0;
        if (C > 64) part += pv1[j] * qv1;
        #pragma unroll
        for (int off = 32; off > 0; off >>= 1) part += __shfl_xor(part, off, 64);
        if (lane == j) { myv = sqnD + sqv - 2.0 * part; mym = pm[j]; }
    }
    unsigned rank = 0;
    for (int i = 0; i < MARGIN; ++i) {
        double vi = __shfl(myv, i, 64);
        int    mi = __shfl(mym, i, 64);
        if (vi < myv || (vi == myv && mi < mym)) ++rank;
    }
    if (lane < MARGIN && rank < KK)
        idx[(size_t)(b * NN + n) * KK + rank] = mym;
}

// ============ UV GEMM fp64, 64-column chunk (L1-3) ============
template<int C>
__global__ void k_uv_d(const double* __restrict__ x, const float* __restrict__ W,
                       const float* __restrict__ bias,
                       double* __restrict__ U, double* __restrict__ V,
                       int Cout, int c0) {
    __shared__ double xt[16 * C];
    const int tid = threadIdx.x;
    const int col = tid & 63;
    const int gcol = c0 + col;
    const int r4 = tid >> 6;
    const int row0 = blockIdx.x * 16;
    for (int t = tid; t < 16 * C; t += 256) xt[t] = x[(size_t)row0 * C + t];
    __syncthreads();
    double u[4] = {0,0,0,0}, v[4] = {0,0,0,0};
    for (int c = 0; c < C; ++c) {
        double wt = (double)W[(size_t)c * Cout + gcol];
        double wd = (double)W[(size_t)(C + c) * Cout + gcol] - wt;
        #pragma unroll
        for (int rr = 0; rr < 4; ++rr) {
            double xv = xt[(r4 * 4 + rr) * C + c];
            u[rr] += xv * wt;
            v[rr] += xv * wd;
        }
    }
    double bb = (double)bias[gcol];
    #pragma unroll
    for (int rr = 0; rr < 4; ++rr) {
        size_t o = (size_t)(row0 + r4 * 4 + rr) * 64 + col;
        U[o] = u[rr] + bb;
        V[o] = v[rr];
    }
}

// ============ gather fp64 (L1-3): XCD-swizzled, barrier-free ============
__global__ __launch_bounds__(256, 4) void k_gath13(const int* __restrict__ idx,
                                                   double* __restrict__ U,
                                                   const double* __restrict__ V,
                                                   double* __restrict__ Hmin,
                                                   double* __restrict__ PS,
                                                   double* __restrict__ PQ) {
    const int lane = threadIdx.x & 63, w = threadIdx.x >> 6;
    int batch, s;
    xcd_decode(blockIdx.x, batch, s);
    const int base = (batch << 10) + (s << 4);
    const int b = batch;
    const int wid = blockIdx.x * 4 + w;
    const int gn0 = base + w * 4;
    double accs = 0.0, accq = 0.0;
    for (int r = 0; r < 4; ++r) {
        int gn = gn0 + r;
        int my = (lane < KK) ? idx[(size_t)gn * KK + lane] : 0;
        double u = U[(size_t)gn * 64 + lane];
        double vmax = -1e300, vmin = 1e300, vs = 0.0, vss = 0.0;
        #pragma unroll
        for (int j = 0; j < KK; ++j) {
            int m = __shfl(my, j, 64);
            double vv = V[(size_t)((b << 10) + m) * 64 + lane];
            vmax = fmax(vmax, vv);
            vmin = fmin(vmin, vv);
            vs  += vv;
            vss += vv * vv;
        }
        accs += (double)KK * u + vs;
        accq += (double)KK * u * u + 2.0 * u * vs + vss;
        U[(size_t)gn * 64 + lane]    = u + vmax;
        Hmin[(size_t)gn * 64 + lane] = u + vmin;
    }
    PS[(size_t)wid * 64 + lane] = accs;
    PQ[(size_t)wid * 64 + lane] = accq;
}

// ============ BN reduce stage 1 (L1-3) ============
template<int CS>
__global__ __launch_bounds__(256) void k_bnred1(const double* __restrict__ PS,
                                                const double* __restrict__ PQ,
                                                double* __restrict__ PS2,
                                                double* __restrict__ PQ2) {
    const int NG = 256 / CS;
    const int tid = threadIdx.x, ch = tid & (CS - 1), grp = tid / CS;
    const int r0 = blockIdx.x * 64;
    double s = 0.0, q = 0.0;
    for (int r = grp; r < 64; r += NG) {
        s += PS[(size_t)(r0 + r) * CS + ch];
        q += PQ[(size_t)(r0 + r) * CS + ch];
    }
    __shared__ double rs[256], rq[256];
    rs[tid] = s; rq[tid] = q;
    __syncthreads();
    if (grp == 0) {
        #pragma unroll
        for (int g = 1; g < NG; ++g) { s += rs[g * CS + ch]; q += rq[g * CS + ch]; }
        PS2[(size_t)blockIdx.x * CS + ch] = s;
        PQ2[(size_t)blockIdx.x * CS + ch] = q;
    }
}

// ============ BN finalize stage 2 (fp64 S/T, L1-3) ============
template<int CS>
__global__ __launch_bounds__(256) void k_bnfin2_d(const double* __restrict__ PS2,
                                                  const double* __restrict__ PQ2,
                                                  const float* __restrict__ g,
                                                  const float* __restrict__ be,
                                                  double* __restrict__ S,
                                                  double* __restrict__ T,
                                                  int c0, int nrows) {
    const int NG = 256 / CS;
    const int tid = threadIdx.x, ch = tid & (CS - 1), grp = tid / CS;
    double s = 0.0, q = 0.0;
    for (int r = grp; r < nrows; r += NG) {
        s += PS2[(size_t)r * CS + ch];
        q += PQ2[(size_t)r * CS + ch];
    }
    __shared__ double rs[256], rq[256];
    rs[tid] = s; rq[tid] = q;
    __syncthreads();
    if (grp == 0) {
        #pragma unroll
        for (int gg = 1; gg < NG; ++gg) { s += rs[gg * CS + ch]; q += rq[gg * CS + ch]; }
        const double M = (double)BN * (double)KK;
        double mean = s / M;
        double var  = q / M - mean * mean;
        if (var < 0.0) var = 0.0;
        double sc = (double)g[c0 + ch] / sqrt(var + 1e-5);
        S[c0 + ch] = sc;
        T[c0 + ch] = (double)be[c0 + ch] - mean * sc;
    }
}

// ============ apply fp64 chunk (L3) ============
__global__ void k_apply_d(const double* __restrict__ Hmax, const double* __restrict__ Hmin,
                          const double* __restrict__ S, const double* __restrict__ T,
                          double* __restrict__ y, int Cout, int c0) {
    const int gn = blockIdx.x, tid = threadIdx.x;
    double s = S[c0 + tid], t = T[c0 + tid];
    double h = (s >= 0.0) ? Hmax[(size_t)gn * 64 + tid] : Hmin[(size_t)gn * 64 + tid];
    y[(size_t)gn * Cout + c0 + tid] = fmax(s * h + t, 0.0);
}

// ============ fused apply+prep (L1/L2), wave per row ============
__global__ void k_applyprep_d(const double* __restrict__ Hmax, const double* __restrict__ Hmin,
                              const double* __restrict__ S, const double* __restrict__ T,
                              double* __restrict__ y, float* __restrict__ yf,
                              double* __restrict__ sqd, float* __restrict__ sqf) {
    const int gn = blockIdx.x, lane = threadIdx.x;   // blockDim = 64
    double s = S[lane], t = T[lane];
    double h = (s >= 0.0) ? Hmax[(size_t)gn * 64 + lane] : Hmin[(size_t)gn * 64 + lane];
    double val = fmax(s * h + t, 0.0);
    y[(size_t)gn * 64 + lane] = val;
    yf[(size_t)gn * 64 + lane] = (float)val;
    double ss = val * val;
    #pragma unroll
    for (int off = 32; off > 0; off >>= 1) ss += __shfl_xor(ss, off, 64);
    if (lane == 0) { sqd[gn] = ss; sqf[gn] = (float)ss; }
}

// ============ layer-4 UV GEMM via bf16 MFMA, bf16 OUTPUTS (halve U/V traffic) ============
__global__ __launch_bounds__(256, 2) void k_uv_mfma(const unsigned short* __restrict__ Xbf,
                                                    const unsigned short* __restrict__ Wtb,
                                                    const unsigned short* __restrict__ Wdb,
                                                    const float* __restrict__ bias,
                                                    unsigned short* __restrict__ U,
                                                    unsigned short* __restrict__ V) {
    __shared__ unsigned short As[64 * 136];
    __shared__ unsigned short Bs[64 * 136];
    const int tid = threadIdx.x, lane = tid & 63, w = tid >> 6;
    const int col0 = blockIdx.x * 64;      // 0..2047
    const int row0 = blockIdx.y * 64;
    const unsigned short* Bsrc = (col0 < 1024) ? (Wtb + (size_t)col0 * 128)
                                               : (Wdb + (size_t)(col0 - 1024) * 128);
    #pragma unroll
    for (int i = 0; i < 4; ++i) {
        int c = tid + i * 256;
        int r = c >> 4, part = c & 15;
        *(int4*)&As[r * 136 + part * 8] =
            *(const int4*)&Xbf[(size_t)(row0 + r) * 128 + part * 8];
        *(int4*)&Bs[r * 136 + part * 8] =
            *(const int4*)&Bsrc[(size_t)r * 128 + part * 8];
    }
    __syncthreads();
    const int quad = lane >> 4, m16 = lane & 15;
    f32x4 acc[4] = {};
    #pragma unroll
    for (int kk = 0; kk < 4; ++kk) {
        bf16x8v af = *(const bf16x8v*)&As[(w * 16 + m16) * 136 + kk * 32 + quad * 8];
        #pragma unroll
        for (int t = 0; t < 4; ++t) {
            bf16x8v bfr = *(const bf16x8v*)&Bs[(t * 16 + m16) * 136 + kk * 32 + quad * 8];
            acc[t] = __builtin_amdgcn_mfma_f32_16x16x32_bf16(af, bfr, acc[t], 0, 0, 0);
        }
    }
    const int rbase = row0 + w * 16 + quad * 4;
    if (col0 < 1024) {
        #pragma unroll
        for (int t = 0; t < 4; ++t) {
            int col = col0 + t * 16 + m16;
            float bb = bias[col];
            #pragma unroll
            for (int r = 0; r < 4; ++r)
                U[(size_t)(rbase + r) * 1024 + col] = f2bf(acc[t][r] + bb);
        }
    } else {
        #pragma unroll
        for (int t = 0; t < 4; ++t) {
            int col = col0 - 1024 + t * 16 + m16;
            #pragma unroll
            for (int r = 0; r < 4; ++r)
                V[(size_t)(rbase + r) * 1024 + col] = f2bf(acc[t][r]);
        }
    }
}

// ============ layer-4 gather v4: bf16 U/V (half traffic), one batch per XCD ============
__global__ __launch_bounds__(256, 4) void k_gath4(const int* __restrict__ idx,
                                                  const unsigned short* __restrict__ U,
                                                  const unsigned short* __restrict__ V,
                                                  unsigned* __restrict__ Zmax,
                                                  unsigned* __restrict__ Zmin,
                                                  double* __restrict__ PS,
                                                  double* __restrict__ PQ) {
    const int tid = threadIdx.x, lane = tid & 63;
    const int p = blockIdx.x;
    const int batch = (p & 7) + ((p >> 10) << 3);
    const int s = (p >> 3) & 127;
    const int gn0 = (batch << 10) + (s << 3);   // 8 rows per block
    const int b = batch;
    const int c4 = tid * 4;
    double accs[4] = {0,0,0,0}, accq[4] = {0,0,0,0};
    float rmax[4] = {-3e38f,-3e38f,-3e38f,-3e38f};
    float rmin[4] = { 3e38f, 3e38f, 3e38f, 3e38f};
    for (int r = 0; r < 8; ++r) {
        int gn = gn0 + r;
        int my = (lane < KK) ? idx[(size_t)gn * KK + lane] : 0;
        u16x4 u4b = __builtin_nontemporal_load((const u16x4*)&U[(size_t)gn * 1024 + c4]);
        float um[4] = {bf2f(u4b[0]), bf2f(u4b[1]), bf2f(u4b[2]), bf2f(u4b[3])};
        float vmax[4] = {-3e38f,-3e38f,-3e38f,-3e38f};
        float vmin[4] = { 3e38f, 3e38f, 3e38f, 3e38f};
        float vs[4] = {0,0,0,0}, vss[4] = {0,0,0,0};
        #pragma unroll
        for (int j = 0; j < KK; ++j) {
            int m = __shfl(my, j, 64);
            u16x4 vv4 = *(const u16x4*)&V[(size_t)((b << 10) + m) * 1024 + c4];
            float vv[4] = {bf2f(vv4[0]), bf2f(vv4[1]), bf2f(vv4[2]), bf2f(vv4[3])};
            #pragma unroll
            for (int e = 0; e < 4; ++e) {
                vmax[e] = fmaxf(vmax[e], vv[e]);
                vmin[e] = fminf(vmin[e], vv[e]);
                vs[e]  += vv[e];
                vss[e] += vv[e] * vv[e];
            }
        }
        #pragma unroll
        for (int e = 0; e < 4; ++e) {
            accs[e] += (double)((float)KK * um[e] + vs[e]);
            accq[e] += (double)((float)KK * um[e] * um[e] + 2.f * um[e] * vs[e] + vss[e]);
            rmax[e] = fmaxf(rmax[e], um[e] + vmax[e]);
            rmin[e] = fminf(rmin[e], um[e] + vmin[e]);
        }
    }
    #pragma unroll
    for (int e = 0; e < 4; ++e) {
        PS[(size_t)p * 1024 + c4 + e] = accs[e];
        PQ[(size_t)p * 1024 + c4 + e] = accq[e];
        atomicMax(&Zmax[b * 1024 + c4 + e], fkey(rmax[e]));
        atomicMin(&Zmin[b * 1024 + c4 + e], fkey(rmin[e]));
    }
}

// ============ L4 BN reduce: 2048 partial rows x 1024 ch ============
__global__ __launch_bounds__(256) void k_bnred1_L4(const double* __restrict__ PS,
                                                   const double* __restrict__ PQ,
                                                   double* __restrict__ PS2,
                                                   double* __restrict__ PQ2) {
    const int ch = (blockIdx.x & 3) * 256 + threadIdx.x;
    const int r0 = (blockIdx.x >> 2) * 64;
    double s = 0.0, q = 0.0;
    for (int r = 0; r < 64; ++r) {
        s += PS[(size_t)(r0 + r) * 1024 + ch];
        q += PQ[(size_t)(r0 + r) * 1024 + ch];
    }
    PS2[(size_t)(blockIdx.x >> 2) * 1024 + ch] = s;
    PQ2[(size_t)(blockIdx.x >> 2) * 1024 + ch] = q;
}

__global__ __launch_bounds__(256) void k_bnfin_L4(const double* __restrict__ PS2,
                                                  const double* __restrict__ PQ2,
                                                  const float* __restrict__ g,
                                                  const float* __restrict__ be,
                                                  float* __restrict__ S,
                                                  float* __restrict__ T) {
    const int ch = blockIdx.x * 256 + threadIdx.x;
    double s = 0.0, q = 0.0;
    for (int r = 0; r < 32; ++r) {
        s += PS2[(size_t)r * 1024 + ch];
        q += PQ2[(size_t)r * 1024 + ch];
    }
    const double M = (double)BN * (double)KK;
    double mean = s / M;
    double var  = q / M - mean * mean;
    if (var < 0.0) var = 0.0;
    float sc = (float)((double)g[ch] / sqrt(var + 1e-5));
    S[ch] = sc;
    T[ch] = (float)((double)be[ch] - mean * (double)sc);
}

// ============ layer-4 finalize ============
__global__ void k_zfin(const unsigned* __restrict__ Zmax, const unsigned* __restrict__ Zmin,
                       const float* __restrict__ S, const float* __restrict__ T,
                       float* __restrict__ z) {
    const int b = blockIdx.y;
    const int c = blockIdx.x * 64 + threadIdx.x;
    float s = S[c], t = T[c];
    float e = (s >= 0.f) ? funkey(Zmax[b * 1024 + c]) : funkey(Zmin[b * 1024 + c]);
    z[(size_t)b * 1024 + c] = fmaxf(s * e + t, 0.f);
}

// ============ FC head ============
__global__ __launch_bounds__(256) void k_fc1(const float* __restrict__ z,
                                             const float* __restrict__ Wc1,
                                             const float* __restrict__ bc1,
                                             float* __restrict__ a1) {
    __shared__ float zs[1024];
    __shared__ float red[256];
    const int b = blockIdx.y, j0 = blockIdx.x * 64;
    const int tid = threadIdx.x, tj = tid & 63, seg = tid >> 6;
    for (int t = tid; t < 1024; t += 256) zs[t] = z[b * 1024 + t];
    __syncthreads();
    float acc = 0.f;
    #pragma unroll 8
    for (int c = seg * 256; c < seg * 256 + 256; ++c)
        acc += zs[c] * Wc1[(size_t)c * 512 + j0 + tj];
    red[tid] = acc;
    __syncthreads();
    if (seg == 0) {
        float s = red[tj] + red[64 + tj] + red[128 + tj] + red[192 + tj] + bc1[j0 + tj];
        a1[b * 512 + j0 + tj] = fmaxf(s, 0.f);
    }
}

__global__ void k_fc2(const float* __restrict__ a1, const float* __restrict__ Wc2,
                      const float* __restrict__ bc2, float* __restrict__ out) {
    const int j = blockIdx.x, b = blockIdx.y, lane = threadIdx.x;
    float acc = 0.f;
    #pragma unroll
    for (int c8 = 0; c8 < 8; ++c8) {
        int c = c8 * 64 + lane;
        acc += a1[b * 512 + c] * Wc2[(size_t)c * 40 + j];
    }
    #pragma unroll
    for (int off = 32; off > 0; off >>= 1) acc += __shfl_xor(acc, off, 64);
    if (lane == 0) out[b * 40 + j] = acc + bc2[j];
}

extern "C" void kernel_launch(void* const* d_in, const int* in_sizes, int n_in,
                              void* d_out, int out_size, void* d_ws, size_t ws_size,
                              hipStream_t stream) {
    const float* pos = (const float*)d_in[0];
    const float* Wc1 = (const float*)d_in[17];
    const float* bc1 = (const float*)d_in[18];
    const float* Wc2 = (const float*)d_in[19];
    const float* bc2 = (const float*)d_in[20];

    char* p = (char*)d_ws;
    auto alloc = [&](size_t bytes) -> void* {
        void* r = (void*)p;
        p += (bytes + 255) & ~(size_t)255;
        return r;
    };
    float*    Dm   = (float*) alloc((size_t)BB * NN * NN * 4);   // 64 MB; aliased as Ufull(bf16) in L4
    unsigned short* Vfull = (unsigned short*)alloc((size_t)BN * 1024 * 2);  // 32 MB bf16 V
    void*     bufA = alloc((size_t)BN * 64 * 8);    // Ud (L1-3)
    void*     bufB = alloc((size_t)BN * 64 * 8);    // Vd
    void*     bufC = alloc((size_t)BN * 64 * 8);    // Hmin (L1-3) / Ybf fp32 (L4)
    double*   Ya   = (double*)alloc((size_t)BN * 64 * 8);
    double*   Yb   = (double*)alloc((size_t)BN * 128 * 8);
    float*    Yaf  = (float*) alloc((size_t)BN * 64 * 4);
    double*   Xd   = (double*)alloc((size_t)BN * 3 * 8);
    double*   SQd  = (double*)alloc((size_t)BN * 8);
    float*    SQf  = (float*) alloc((size_t)BN * 4);
    int*      IDX  = (int*)   alloc((size_t)BN * KK * 4);
    unsigned short* Xbf = (unsigned short*)alloc((size_t)BN * 128 * 2);  // 4 MB bf16 X
    unsigned short* Wtb = (unsigned short*)alloc((size_t)1024 * 128 * 2);
    unsigned short* Wdb = (unsigned short*)alloc((size_t)1024 * 128 * 2);
    double*   PARTS= (double*)alloc((size_t)4096 * 64 * 8);
    double*   PARTQ= (double*)alloc((size_t)4096 * 64 * 8);
    double*   PS2  = (double*)alloc((size_t)64 * 128 * 8);
    double*   PQ2  = (double*)alloc((size_t)64 * 128 * 8);
    double*   PL4S = (double*)alloc((size_t)2048 * 1024 * 8);  // 16 MB (2048 partial rows)
    double*   PL4Q = (double*)alloc((size_t)2048 * 1024 * 8);
    double*   PL4S2= (double*)alloc((size_t)32 * 1024 * 8);
    double*   PL4Q2= (double*)alloc((size_t)32 * 1024 * 8);
    double*   Sd   = (double*)alloc((size_t)128 * 8);
    double*   Td   = (double*)alloc((size_t)128 * 8);
    float*    Sf   = (float*) alloc((size_t)1024 * 4);
    float*    Tf   = (float*) alloc((size_t)1024 * 4);
    unsigned* Zmax = (unsigned*)alloc((size_t)BB * 1024 * 4);
    unsigned* Zmin = (unsigned*)alloc((size_t)BB * 1024 * 4);
    float*    Z    = (float*) alloc((size_t)BB * 1024 * 4);
    float*    A1   = (float*) alloc((size_t)BB * 512 * 4);
    // total ~= 207 MB (ws = 256 MiB)

    double* Ud = (double*)bufA; double* Vd = (double*)bufB; double* Hd = (double*)bufC;
    float*  Ybf = (float*)bufC;
    unsigned short* Ufull = (unsigned short*)Dm;  // D dead after L4 select; reuse (needs 32 MB)

    hipMemsetAsync(Zmax, 0x00, (size_t)BB * 1024 * 4, stream);
    hipMemsetAsync(Zmin, 0xFF, (size_t)BB * 1024 * 4, stream);

    k_cast3<<<(BN + 255) / 256, 256, 0, stream>>>(pos, Xd, SQd, SQf);
    k_wprep<<<dim3(16, 4), 256, 0, stream>>>((const float*)d_in[13], Wtb, Wdb);

    // ---- Layer 1: C=3 -> 64 ----
    {
        const float* W = (const float*)d_in[1], *bs = (const float*)d_in[2];
        const float* g = (const float*)d_in[3], *be = (const float*)d_in[4];
        k_dist<3><<<dim3(136, 1, BB), 256, 0, stream>>>(pos, SQf, Dm);
        k_select<3><<<dim3(NN / 4, BB), 256, 0, stream>>>(Dm, Xd, SQd, IDX);
        k_uv_d<3><<<BN / 16, 256, 0, stream>>>(Xd, W, bs, Ud, Vd, 64, 0);
        k_gath13<<<BN / 16, 256, 0, stream>>>(IDX, Ud, Vd, Hd, PARTS, PARTQ);
        k_bnred1<64><<<64, 256, 0, stream>>>(PARTS, PARTQ, PS2, PQ2);
        k_bnfin2_d<64><<<1, 256, 0, stream>>>(PS2, PQ2, g, be, Sd, Td, 0, 64);
        k_applyprep_d<<<BN, 64, 0, stream>>>(Ud, Hd, Sd, Td, Ya, Yaf, SQd, SQf);
    }
    // ---- Layer 2: C=64 -> 64 ----
    {
        const float* W = (const float*)d_in[5], *bs = (const float*)d_in[6];
        const float* g = (const float*)d_in[7], *be = (const float*)d_in[8];
        k_dist<64><<<dim3(136, 1, BB), 256, 0, stream>>>(Yaf, SQf, Dm);
        k_select<64><<<dim3(NN / 4, BB), 256, 0, stream>>>(Dm, Ya, SQd, IDX);
        k_uv_d<64><<<BN / 16, 256, 0, stream>>>(Ya, W, bs, Ud, Vd, 64, 0);
        k_gath13<<<BN / 16, 256, 0, stream>>>(IDX, Ud, Vd, Hd, PARTS, PARTQ);
        k_bnred1<64><<<64, 256, 0, stream>>>(PARTS, PARTQ, PS2, PQ2);
        k_bnfin2_d<64><<<1, 256, 0, stream>>>(PS2, PQ2, g, be, Sd, Td, 0, 64);
        k_applyprep_d<<<BN, 64, 0, stream>>>(Ud, Hd, Sd, Td, Ya, Yaf, SQd, SQf);
    }
    // ---- Layer 3: C=64 -> 128, two 64-col chunks, Ya -> Yb ----
    {
        const float* W = (const float*)d_in[9], *bs = (const float*)d_in[10];
        const float* g = (const float*)d_in[11], *be = (const float*)d_in[12];
        k_dist<64><<<dim3(136, 1, BB), 256, 0, stream>>>(Yaf, SQf, Dm);
        k_select<64><<<dim3(NN / 4, BB), 256, 0, stream>>>(Dm, Ya, SQd, IDX);
        for (int cc = 0; cc < 2; ++cc) {
            const int c0 = cc * 64;
            k_uv_d<64><<<BN / 16, 256, 0, stream>>>(Ya, W, bs, Ud, Vd, 128, c0);
            k_gath13<<<BN / 16, 256, 0, stream>>>(IDX, Ud, Vd, Hd, PARTS, PARTQ);
            k_bnred1<64><<<64, 256, 0, stream>>>(PARTS, PARTQ, PS2, PQ2);
            k_bnfin2_d<64><<<1, 256, 0, stream>>>(PS2, PQ2, g, be, Sd, Td, c0, 64);
            k_apply_d<<<BN, 64, 0, stream>>>(Ud, Hd, Sd, Td, Yb, 128, c0);
        }
        k_prep<<<BN / 4, 256, 0, stream>>>(Yb, Ybf, SQd, SQf, 128);   // Ybf = bufC
    }
    // ---- Layer 4: C=128 -> 1024, bf16 MFMA UV (bf16 out) + single-pass gather ----
    {
        const float* bs = (const float*)d_in[14];
        const float* g = (const float*)d_in[15], *be = (const float*)d_in[16];
        k_dist<128><<<dim3(136, 1, BB), 256, 0, stream>>>(Ybf, SQf, Dm);
        k_select<128><<<dim3(NN / 4, BB), 256, 0, stream>>>(Dm, Yb, SQd, IDX);
        k_xcast<<<BN * 128 / 2048, 256, 0, stream>>>(Yb, Xbf);
        // Dm is now dead -> Ufull (bf16) aliases it
        k_uv_mfma<<<dim3(32, BN / 64), 256, 0, stream>>>(Xbf, Wtb, Wdb, bs, Ufull, Vfull);
        k_gath4<<<2048, 256, 0, stream>>>(IDX, Ufull, Vfull, Zmax, Zmin, PL4S, PL4Q);
        k_bnred1_L4<<<128, 256, 0, stream>>>(PL4S, PL4Q, PL4S2, PL4Q2);
        k_bnfin_L4<<<4, 256, 0, stream>>>(PL4S2, PL4Q2, g, be, Sf, Tf);
        k_zfin<<<dim3(16, BB), 64, 0, stream>>>(Zmax, Zmin, Sf, Tf, Z);
    }

    k_fc1<<<dim3(8, BB), 256, 0, stream>>>(Z, Wc1, bc1, A1);
    k_fc2<<<dim3(40, BB), 64, 0, stream>>>(A1, Wc2, bc2, (float*)d_out);
}

// Round 19
// 863.917 us; speedup vs baseline: 1.2023x; 1.1103x over previous
//
#include <hip/hip_runtime.h>
#include <hip/hip_bf16.h>

#define BB 16
#define NN 1024
#define BN (BB*NN)
#define KK 20
#define MARGIN 25   // fp32 prefilter width (>= KK + safety)

typedef short bf16x8v __attribute__((ext_vector_type(8)));
typedef float f32x4   __attribute__((ext_vector_type(4)));
typedef unsigned short u16x4 __attribute__((ext_vector_type(4)));

// monotone float <-> uint key for atomic max/min (handles negatives)
__device__ inline unsigned fkey(float x) {
    unsigned b = __float_as_uint(x);
    return (b & 0x80000000u) ? ~b : (b | 0x80000000u);
}
__device__ inline float funkey(unsigned k) {
    unsigned b = (k & 0x80000000u) ? (k ^ 0x80000000u) : ~k;
    return __uint_as_float(b);
}
// fp32 -> bf16 bits, round-to-nearest-even
__device__ inline unsigned short f2bf(float x) {
    unsigned u = __float_as_uint(x);
    return (unsigned short)((u + 0x7FFFu + ((u >> 16) & 1u)) >> 16);
}
__device__ inline float bf2f(unsigned short u) {
    return __uint_as_float((unsigned)u << 16);
}

// XCD-aware swizzle (L1-3 gather): 1024 blocks = 16 batches x 64 subs.
__device__ inline void xcd_decode(int p, int& batch, int& s) {
    int xcd = p & 7, rem = p >> 3;
    s = rem & 63;
    batch = xcd + ((rem >> 6) << 3);
}

// ============ cast pos -> double + row sqnorm (fp64 + fp32) ============
__global__ void k_cast3(const float* __restrict__ pos, double* __restrict__ xd,
                        double* __restrict__ sqd, float* __restrict__ sqf) {
    int gn = blockIdx.x * blockDim.x + threadIdx.x;
    if (gn >= BN) return;
    double s = 0.0;
    #pragma unroll
    for (int c = 0; c < 3; ++c) {
        double v = (double)pos[gn * 3 + c];
        xd[gn * 3 + c] = v;
        s += v * v;
    }
    sqd[gn] = s;
    sqf[gn] = (float)s;
}

// ============ prep: fp64 y -> fp32 copy + sqnorms (fp64 + fp32) ============
__global__ void k_prep(const double* __restrict__ y, float* __restrict__ yf,
                       double* __restrict__ sqd, float* __restrict__ sqf, int C) {
    const int row = blockIdx.x * 4 + (threadIdx.x >> 6);
    const int lane = threadIdx.x & 63;
    const double* yr = y + (size_t)row * C;
    float* yfr = yf + (size_t)row * C;
    double s = 0.0;
    for (int c = lane; c < C; c += 64) {
        double v = yr[c];
        s += v * v;
        yfr[c] = (float)v;
    }
    #pragma unroll
    for (int off = 32; off > 0; off >>= 1) s += __shfl_xor(s, off, 64);
    if (lane == 0) { sqd[row] = s; sqf[row] = (float)s; }
}

// ============ W4 prep: transpose + bf16 + diff. W(256x1024) -> Wtb/Wdb [1024][128] ============
__global__ __launch_bounds__(256) void k_wprep(const float* __restrict__ W,
                                               unsigned short* __restrict__ Wtb,
                                               unsigned short* __restrict__ Wdb) {
    __shared__ float Lt[32][65], Ld[32][65];
    const int n0 = blockIdx.x * 64, k0 = blockIdx.y * 32;
    const int tid = threadIdx.x;
    {
        const int nn = tid & 63, kg = tid >> 6;
        #pragma unroll
        for (int i = 0; i < 8; ++i) {
            int kk = kg * 8 + i;
            float wt = W[(size_t)(k0 + kk) * 1024 + n0 + nn];
            float wb = W[(size_t)(128 + k0 + kk) * 1024 + n0 + nn];
            Lt[kk][nn] = wt;
            Ld[kk][nn] = wb - wt;
        }
    }
    __syncthreads();
    {
        const int kk = tid & 31, ng = tid >> 5;
        #pragma unroll
        for (int i = 0; i < 8; ++i) {
            int nl = ng + i * 8;
            Wtb[(size_t)(n0 + nl) * 128 + k0 + kk] = f2bf(Lt[kk][nl]);
            Wdb[(size_t)(n0 + nl) * 128 + k0 + kk] = f2bf(Ld[kk][nl]);
        }
    }
}

// ============ Yb (fp64, 16K x 128) -> bf16 bits ============
__global__ void k_xcast(const double* __restrict__ y, unsigned short* __restrict__ xb) {
    const size_t t = (size_t)blockIdx.x * 256 + threadIdx.x;   // chunk of 8
    const double* src = y + t * 8;
    unsigned short o[8];
    #pragma unroll
    for (int i = 0; i < 8; ++i) o[i] = f2bf((float)src[i]);
    *(int4*)&xb[t * 8] = *(int4*)o;
}

// ============ distance matrix GEMM, symmetric-triangle, all 16 batches ============
template<int C>
__global__ __launch_bounds__(256, 3) void k_dist(const float* __restrict__ xf,
                                                 const float* __restrict__ sqf,
                                                 float* __restrict__ D) {
    const int b = blockIdx.z;
    const float* xb = xf + (size_t)b * NN * C;
    int t = blockIdx.x;
    int ti = (int)((sqrtf(8.f * t + 1.f) - 1.f) * 0.5f);
    while (ti * (ti + 1) / 2 > t) --ti;
    while ((ti + 1) * (ti + 2) / 2 <= t) ++ti;
    const int tj = t - ti * (ti + 1) / 2;
    const int tx = threadIdx.x & 15, ty = threadIdx.x >> 4;
    const int row0 = ti * 64, col0 = tj * 64;
    float acc[4][4] = {};
    if constexpr (C == 3) {
        float ar[4][3], bc[4][3];
        #pragma unroll
        for (int i = 0; i < 4; ++i)
            #pragma unroll
            for (int c = 0; c < 3; ++c) {
                ar[i][c] = xb[(size_t)(row0 + ty * 4 + i) * 3 + c];
                bc[i][c] = xb[(size_t)(col0 + tx * 4 + i) * 3 + c];
            }
        #pragma unroll
        for (int i = 0; i < 4; ++i)
            #pragma unroll
            for (int j = 0; j < 4; ++j)
                acc[i][j] = ar[i][0]*bc[j][0] + ar[i][1]*bc[j][1] + ar[i][2]*bc[j][2];
    } else {
        __shared__ float As[32][65], Bs[32][65];
        for (int k0 = 0; k0 < C; k0 += 32) {
            for (int tt = threadIdx.x; tt < 512; tt += 256) {
                int r = tt >> 3, kq = (tt & 7) * 4;
                float4 va = *(const float4*)&xb[(size_t)(row0 + r) * C + k0 + kq];
                As[kq+0][r] = va.x; As[kq+1][r] = va.y; As[kq+2][r] = va.z; As[kq+3][r] = va.w;
                float4 vb = *(const float4*)&xb[(size_t)(col0 + r) * C + k0 + kq];
                Bs[kq+0][r] = vb.x; Bs[kq+1][r] = vb.y; Bs[kq+2][r] = vb.z; Bs[kq+3][r] = vb.w;
            }
            __syncthreads();
            #pragma unroll 4
            for (int kk = 0; kk < 32; ++kk) {
                float a[4], bb[4];
                #pragma unroll
                for (int i = 0; i < 4; ++i) { a[i] = As[kk][ty*4+i]; bb[i] = Bs[kk][tx*4+i]; }
                #pragma unroll
                for (int i = 0; i < 4; ++i)
                    #pragma unroll
                    for (int j = 0; j < 4; ++j)
                        acc[i][j] += a[i] * bb[j];
            }
            __syncthreads();
        }
    }
    float sr[4], sc[4];
    #pragma unroll
    for (int i = 0; i < 4; ++i) {
        sr[i] = sqf[b * NN + row0 + ty * 4 + i];
        sc[i] = sqf[b * NN + col0 + tx * 4 + i];
    }
    float* Dp = D + (size_t)b * NN * NN;
    #pragma unroll
    for (int i = 0; i < 4; ++i) {
        int r = row0 + ty * 4 + i;
        float4 st;
        float* e = &st.x;
        #pragma unroll
        for (int j = 0; j < 4; ++j) {
            float v = sr[i] + sc[j] - 2.f * acc[i][j];
            if (r == col0 + tx * 4 + j) v += 1e10f;
            e[j] = v;
        }
        *(float4*)&Dp[(size_t)r * NN + col0 + tx * 4] = st;
    }
    if (ti != tj) {
        #pragma unroll
        for (int j = 0; j < 4; ++j) {
            int c = col0 + tx * 4 + j;
            float4 st;
            st.x = sr[0] + sc[j] - 2.f * acc[0][j];
            st.y = sr[1] + sc[j] - 2.f * acc[1][j];
            st.z = sr[2] + sc[j] - 2.f * acc[2][j];
            st.w = sr[3] + sc[j] - 2.f * acc[3][j];
            *(float4*)&Dp[(size_t)c * NN + row0 + ty * 4] = st;
        }
    }
}

// ============ selection v3: u32 top-MARGIN + transposed fp64 re-rank ============
// Phase 3: lane j (<MARGIN) OWNS candidate j and computes its fp64 distance
// serially over C (no cross-lane reductions). Order-robust: fp64 reassoc noise
// ~1e-16 << inter-candidate gaps.
template<int C>
__global__ __launch_bounds__(256, 4) void k_select(const float* __restrict__ D,
                                                   const double* __restrict__ xd,
                                                   const double* __restrict__ sqd,
                                                   int* __restrict__ idx) {
    const int lane = threadIdx.x & 63, w = threadIdx.x >> 6;
    const int n = blockIdx.x * 4 + w;
    const int b = blockIdx.y;
    const float* Drow = D + ((size_t)b * NN + n) * NN;

    unsigned key[16];
    const float4* dv = (const float4*)(Drow + lane * 16);
    #pragma unroll
    for (int q = 0; q < 4; ++q) {
        float4 v = dv[q];
        key[q*4+0] = (fkey(v.x) & 0xFFFFFFF0u) | (unsigned)(q*4+0);
        key[q*4+1] = (fkey(v.y) & 0xFFFFFFF0u) | (unsigned)(q*4+1);
        key[q*4+2] = (fkey(v.z) & 0xFFFFFFF0u) | (unsigned)(q*4+2);
        key[q*4+3] = (fkey(v.w) & 0xFFFFFFF0u) | (unsigned)(q*4+3);
    }
    unsigned lmin = key[0];
    #pragma unroll
    for (int c = 1; c < 16; ++c) lmin = min(lmin, key[c]);

    int pickm = 0x7FFFFFFF;
    #pragma unroll
    for (int it = 0; it < MARGIN; ++it) {
        unsigned gmin = lmin;
        #pragma unroll
        for (int off = 32; off > 0; off >>= 1)
            gmin = min(gmin, (unsigned)__shfl_xor((int)gmin, off, 64));
        unsigned long long msk = __ballot(lmin == gmin);
        int L = (int)__ffsll(msk) - 1;
        int m = L * 16 + (int)(gmin & 15u);
        if (lane == it) pickm = m;
        if (lane == L) {
            int jj = (int)(gmin & 15u);
            #pragma unroll
            for (int c = 0; c < 16; ++c) if (c == jj) key[c] = 0xFFFFFFFFu;
            lmin = key[0];
            #pragma unroll
            for (int c = 1; c < 16; ++c) lmin = min(lmin, key[c]);
        }
    }

    // ---- phase 3: transposed fp64 re-rank (lane j owns candidate j) ----
    const double* xdb  = xd + (size_t)b * NN * C;
    const double* sqdb = sqd + b * NN;
    double myv = 1e300; int mym = 0x7FFFFFFF;
    if (lane < MARGIN) {
        mym = pickm;
        const double* cand = xdb + (size_t)mym * C;
        const double* qrow = xdb + (size_t)n * C;
        double dot;
        if constexpr (C == 3) {
            dot = cand[0]*qrow[0] + cand[1]*qrow[1] + cand[2]*qrow[2];
        } else {
            double d0 = 0.0, d1 = 0.0, d2 = 0.0, d3 = 0.0;
            #pragma unroll 4
            for (int c = 0; c < C; c += 4) {
                d0 += cand[c+0] * qrow[c+0];
                d1 += cand[c+1] * qrow[c+1];
                d2 += cand[c+2] * qrow[c+2];
                d3 += cand[c+3] * qrow[c+3];
            }
            dot = (d0 + d1) + (d2 + d3);
        }
        myv = sqdb[n] + sqdb[mym] - 2.0 * dot;
    }
    unsigned rank = 0;
    for (int i = 0; i < MARGIN; ++i) {
        double vi = __shfl(myv, i, 64);
        int    mi = __shfl(mym, i, 64);
        if (vi < myv || (vi == myv && mi < mym)) ++rank;
    }
    if (lane < MARGIN && rank < KK)
        idx[(size_t)(b * NN + n) * KK + rank] = mym;
}

// ============ UV GEMM fp64, 64-column chunk (L1-3) ============
template<int C>
__global__ void k_uv_d(const double* __restrict__ x, const float* __restrict__ W,
                       const float* __restrict__ bias,
                       double* __restrict__ U, double* __restrict__ V,
                       int Cout, int c0) {
    __shared__ double xt[16 * C];
    const int tid = threadIdx.x;
    const int col = tid & 63;
    const int gcol = c0 + col;
    const int r4 = tid >> 6;
    const int row0 = blockIdx.x * 16;
    for (int t = tid; t < 16 * C; t += 256) xt[t] = x[(size_t)row0 * C + t];
    __syncthreads();
    double u[4] = {0,0,0,0}, v[4] = {0,0,0,0};
    for (int c = 0; c < C; ++c) {
        double wt = (double)W[(size_t)c * Cout + gcol];
        double wd = (double)W[(size_t)(C + c) * Cout + gcol] - wt;
        #pragma unroll
        for (int rr = 0; rr < 4; ++rr) {
            double xv = xt[(r4 * 4 + rr) * C + c];
            u[rr] += xv * wt;
            v[rr] += xv * wd;
        }
    }
    double bb = (double)bias[gcol];
    #pragma unroll
    for (int rr = 0; rr < 4; ++rr) {
        size_t o = (size_t)(row0 + r4 * 4 + rr) * 64 + col;
        U[o] = u[rr] + bb;
        V[o] = v[rr];
    }
}

// ============ gather fp64 (L1-3): XCD-swizzled, barrier-free ============
__global__ __launch_bounds__(256, 4) void k_gath13(const int* __restrict__ idx,
                                                   double* __restrict__ U,
                                                   const double* __restrict__ V,
                                                   double* __restrict__ Hmin,
                                                   double* __restrict__ PS,
                                                   double* __restrict__ PQ) {
    const int lane = threadIdx.x & 63, w = threadIdx.x >> 6;
    int batch, s;
    xcd_decode(blockIdx.x, batch, s);
    const int base = (batch << 10) + (s << 4);
    const int b = batch;
    const int wid = blockIdx.x * 4 + w;
    const int gn0 = base + w * 4;
    double accs = 0.0, accq = 0.0;
    for (int r = 0; r < 4; ++r) {
        int gn = gn0 + r;
        int my = (lane < KK) ? idx[(size_t)gn * KK + lane] : 0;
        double u = U[(size_t)gn * 64 + lane];
        double vmax = -1e300, vmin = 1e300, vs = 0.0, vss = 0.0;
        #pragma unroll
        for (int j = 0; j < KK; ++j) {
            int m = __shfl(my, j, 64);
            double vv = V[(size_t)((b << 10) + m) * 64 + lane];
            vmax = fmax(vmax, vv);
            vmin = fmin(vmin, vv);
            vs  += vv;
            vss += vv * vv;
        }
        accs += (double)KK * u + vs;
        accq += (double)KK * u * u + 2.0 * u * vs + vss;
        U[(size_t)gn * 64 + lane]    = u + vmax;
        Hmin[(size_t)gn * 64 + lane] = u + vmin;
    }
    PS[(size_t)wid * 64 + lane] = accs;
    PQ[(size_t)wid * 64 + lane] = accq;
}

// ============ BN reduce stage 1 (L1-3) ============
template<int CS>
__global__ __launch_bounds__(256) void k_bnred1(const double* __restrict__ PS,
                                                const double* __restrict__ PQ,
                                                double* __restrict__ PS2,
                                                double* __restrict__ PQ2) {
    const int NG = 256 / CS;
    const int tid = threadIdx.x, ch = tid & (CS - 1), grp = tid / CS;
    const int r0 = blockIdx.x * 64;
    double s = 0.0, q = 0.0;
    for (int r = grp; r < 64; r += NG) {
        s += PS[(size_t)(r0 + r) * CS + ch];
        q += PQ[(size_t)(r0 + r) * CS + ch];
    }
    __shared__ double rs[256], rq[256];
    rs[tid] = s; rq[tid] = q;
    __syncthreads();
    if (grp == 0) {
        #pragma unroll
        for (int g = 1; g < NG; ++g) { s += rs[g * CS + ch]; q += rq[g * CS + ch]; }
        PS2[(size_t)blockIdx.x * CS + ch] = s;
        PQ2[(size_t)blockIdx.x * CS + ch] = q;
    }
}

// ============ BN finalize stage 2 (fp64 S/T, L1-3) ============
template<int CS>
__global__ __launch_bounds__(256) void k_bnfin2_d(const double* __restrict__ PS2,
                                                  const double* __restrict__ PQ2,
                                                  const float* __restrict__ g,
                                                  const float* __restrict__ be,
                                                  double* __restrict__ S,
                                                  double* __restrict__ T,
                                                  int c0, int nrows) {
    const int NG = 256 / CS;
    const int tid = threadIdx.x, ch = tid & (CS - 1), grp = tid / CS;
    double s = 0.0, q = 0.0;
    for (int r = grp; r < nrows; r += NG) {
        s += PS2[(size_t)r * CS + ch];
        q += PQ2[(size_t)r * CS + ch];
    }
    __shared__ double rs[256], rq[256];
    rs[tid] = s; rq[tid] = q;
    __syncthreads();
    if (grp == 0) {
        #pragma unroll
        for (int gg = 1; gg < NG; ++gg) { s += rs[gg * CS + ch]; q += rq[gg * CS + ch]; }
        const double M = (double)BN * (double)KK;
        double mean = s / M;
        double var  = q / M - mean * mean;
        if (var < 0.0) var = 0.0;
        double sc = (double)g[c0 + ch] / sqrt(var + 1e-5);
        S[c0 + ch] = sc;
        T[c0 + ch] = (double)be[c0 + ch] - mean * sc;
    }
}

// ============ apply fp64 chunk (L3) ============
__global__ void k_apply_d(const double* __restrict__ Hmax, const double* __restrict__ Hmin,
                          const double* __restrict__ S, const double* __restrict__ T,
                          double* __restrict__ y, int Cout, int c0) {
    const int gn = blockIdx.x, tid = threadIdx.x;
    double s = S[c0 + tid], t = T[c0 + tid];
    double h = (s >= 0.0) ? Hmax[(size_t)gn * 64 + tid] : Hmin[(size_t)gn * 64 + tid];
    y[(size_t)gn * Cout + c0 + tid] = fmax(s * h + t, 0.0);
}

// ============ fused apply+prep (L1/L2), wave per row ============
__global__ void k_applyprep_d(const double* __restrict__ Hmax, const double* __restrict__ Hmin,
                              const double* __restrict__ S, const double* __restrict__ T,
                              double* __restrict__ y, float* __restrict__ yf,
                              double* __restrict__ sqd, float* __restrict__ sqf) {
    const int gn = blockIdx.x, lane = threadIdx.x;   // blockDim = 64
    double s = S[lane], t = T[lane];
    double h = (s >= 0.0) ? Hmax[(size_t)gn * 64 + lane] : Hmin[(size_t)gn * 64 + lane];
    double val = fmax(s * h + t, 0.0);
    y[(size_t)gn * 64 + lane] = val;
    yf[(size_t)gn * 64 + lane] = (float)val;
    double ss = val * val;
    #pragma unroll
    for (int off = 32; off > 0; off >>= 1) ss += __shfl_xor(ss, off, 64);
    if (lane == 0) { sqd[gn] = ss; sqf[gn] = (float)ss; }
}

// ============ layer-4 UV GEMM via bf16 MFMA, bf16 OUTPUTS ============
__global__ __launch_bounds__(256, 2) void k_uv_mfma(const unsigned short* __restrict__ Xbf,
                                                    const unsigned short* __restrict__ Wtb,
                                                    const unsigned short* __restrict__ Wdb,
                                                    const float* __restrict__ bias,
                                                    unsigned short* __restrict__ U,
                                                    unsigned short* __restrict__ V) {
    __shared__ unsigned short As[64 * 136];
    __shared__ unsigned short Bs[64 * 136];
    const int tid = threadIdx.x, lane = tid & 63, w = tid >> 6;
    const int col0 = blockIdx.x * 64;      // 0..2047
    const int row0 = blockIdx.y * 64;
    const unsigned short* Bsrc = (col0 < 1024) ? (Wtb + (size_t)col0 * 128)
                                               : (Wdb + (size_t)(col0 - 1024) * 128);
    #pragma unroll
    for (int i = 0; i < 4; ++i) {
        int c = tid + i * 256;
        int r = c >> 4, part = c & 15;
        *(int4*)&As[r * 136 + part * 8] =
            *(const int4*)&Xbf[(size_t)(row0 + r) * 128 + part * 8];
        *(int4*)&Bs[r * 136 + part * 8] =
            *(const int4*)&Bsrc[(size_t)r * 128 + part * 8];
    }
    __syncthreads();
    const int quad = lane >> 4, m16 = lane & 15;
    f32x4 acc[4] = {};
    #pragma unroll
    for (int kk = 0; kk < 4; ++kk) {
        bf16x8v af = *(const bf16x8v*)&As[(w * 16 + m16) * 136 + kk * 32 + quad * 8];
        #pragma unroll
        for (int t = 0; t < 4; ++t) {
            bf16x8v bfr = *(const bf16x8v*)&Bs[(t * 16 + m16) * 136 + kk * 32 + quad * 8];
            acc[t] = __builtin_amdgcn_mfma_f32_16x16x32_bf16(af, bfr, acc[t], 0, 0, 0);
        }
    }
    const int rbase = row0 + w * 16 + quad * 4;
    if (col0 < 1024) {
        #pragma unroll
        for (int t = 0; t < 4; ++t) {
            int col = col0 + t * 16 + m16;
            float bb = bias[col];
            #pragma unroll
            for (int r = 0; r < 4; ++r)
                U[(size_t)(rbase + r) * 1024 + col] = f2bf(acc[t][r] + bb);
        }
    } else {
        #pragma unroll
        for (int t = 0; t < 4; ++t) {
            int col = col0 - 1024 + t * 16 + m16;
            #pragma unroll
            for (int r = 0; r < 4; ++r)
                V[(size_t)(rbase + r) * 1024 + col] = f2bf(acc[t][r]);
        }
    }
}

// ============ layer-4 gather: bf16 U/V, one batch per XCD resident set ============
__global__ __launch_bounds__(256, 4) void k_gath4(const int* __restrict__ idx,
                                                  const unsigned short* __restrict__ U,
                                                  const unsigned short* __restrict__ V,
                                                  unsigned* __restrict__ Zmax,
                                                  unsigned* __restrict__ Zmin,
                                                  double* __restrict__ PS,
                                                  double* __restrict__ PQ) {
    const int tid = threadIdx.x, lane = tid & 63;
    const int p = blockIdx.x;
    const int batch = (p & 7) + ((p >> 10) << 3);
    const int s = (p >> 3) & 127;
    const int gn0 = (batch << 10) + (s << 3);   // 8 rows per block
    const int b = batch;
    const int c4 = tid * 4;
    double accs[4] = {0,0,0,0}, accq[4] = {0,0,0,0};
    float rmax[4] = {-3e38f,-3e38f,-3e38f,-3e38f};
    float rmin[4] = { 3e38f, 3e38f, 3e38f, 3e38f};
    for (int r = 0; r < 8; ++r) {
        int gn = gn0 + r;
        int my = (lane < KK) ? idx[(size_t)gn * KK + lane] : 0;
        u16x4 u4b = __builtin_nontemporal_load((const u16x4*)&U[(size_t)gn * 1024 + c4]);
        float um[4] = {bf2f(u4b[0]), bf2f(u4b[1]), bf2f(u4b[2]), bf2f(u4b[3])};
        float vmax[4] = {-3e38f,-3e38f,-3e38f,-3e38f};
        float vmin[4] = { 3e38f, 3e38f, 3e38f, 3e38f};
        float vs[4] = {0,0,0,0}, vss[4] = {0,0,0,0};
        #pragma unroll
        for (int j = 0; j < KK; ++j) {
            int m = __shfl(my, j, 64);
            u16x4 vv4 = *(const u16x4*)&V[(size_t)((b << 10) + m) * 1024 + c4];
            float vv[4] = {bf2f(vv4[0]), bf2f(vv4[1]), bf2f(vv4[2]), bf2f(vv4[3])};
            #pragma unroll
            for (int e = 0; e < 4; ++e) {
                vmax[e] = fmaxf(vmax[e], vv[e]);
                vmin[e] = fminf(vmin[e], vv[e]);
                vs[e]  += vv[e];
                vss[e] += vv[e] * vv[e];
            }
        }
        #pragma unroll
        for (int e = 0; e < 4; ++e) {
            accs[e] += (double)((float)KK * um[e] + vs[e]);
            accq[e] += (double)((float)KK * um[e] * um[e] + 2.f * um[e] * vs[e] + vss[e]);
            rmax[e] = fmaxf(rmax[e], um[e] + vmax[e]);
            rmin[e] = fminf(rmin[e], um[e] + vmin[e]);
        }
    }
    #pragma unroll
    for (int e = 0; e < 4; ++e) {
        PS[(size_t)p * 1024 + c4 + e] = accs[e];
        PQ[(size_t)p * 1024 + c4 + e] = accq[e];
        atomicMax(&Zmax[b * 1024 + c4 + e], fkey(rmax[e]));
        atomicMin(&Zmin[b * 1024 + c4 + e], fkey(rmin[e]));
    }
}

// ============ L4 BN reduce: 2048 partial rows x 1024 ch ============
__global__ __launch_bounds__(256) void k_bnred1_L4(const double* __restrict__ PS,
                                                   const double* __restrict__ PQ,
                                                   double* __restrict__ PS2,
                                                   double* __restrict__ PQ2) {
    const int ch = (blockIdx.x & 3) * 256 + threadIdx.x;
    const int r0 = (blockIdx.x >> 2) * 64;
    double s = 0.0, q = 0.0;
    for (int r = 0; r < 64; ++r) {
        s += PS[(size_t)(r0 + r) * 1024 + ch];
        q += PQ[(size_t)(r0 + r) * 1024 + ch];
    }
    PS2[(size_t)(blockIdx.x >> 2) * 1024 + ch] = s;
    PQ2[(size_t)(blockIdx.x >> 2) * 1024 + ch] = q;
}

__global__ __launch_bounds__(256) void k_bnfin_L4(const double* __restrict__ PS2,
                                                  const double* __restrict__ PQ2,
                                                  const float* __restrict__ g,
                                                  const float* __restrict__ be,
                                                  float* __restrict__ S,
                                                  float* __restrict__ T) {
    const int ch = blockIdx.x * 256 + threadIdx.x;
    double s = 0.0, q = 0.0;
    for (int r = 0; r < 32; ++r) {
        s += PS2[(size_t)r * 1024 + ch];
        q += PQ2[(size_t)r * 1024 + ch];
    }
    const double M = (double)BN * (double)KK;
    double mean = s / M;
    double var  = q / M - mean * mean;
    if (var < 0.0) var = 0.0;
    float sc = (float)((double)g[ch] / sqrt(var + 1e-5));
    S[ch] = sc;
    T[ch] = (float)((double)be[ch] - mean * (double)sc);
}

// ============ layer-4 finalize ============
__global__ void k_zfin(const unsigned* __restrict__ Zmax, const unsigned* __restrict__ Zmin,
                       const float* __restrict__ S, const float* __restrict__ T,
                       float* __restrict__ z) {
    const int b = blockIdx.y;
    const int c = blockIdx.x * 64 + threadIdx.x;
    float s = S[c], t = T[c];
    float e = (s >= 0.f) ? funkey(Zmax[b * 1024 + c]) : funkey(Zmin[b * 1024 + c]);
    z[(size_t)b * 1024 + c] = fmaxf(s * e + t, 0.f);
}

// ============ FC head ============
__global__ __launch_bounds__(256) void k_fc1(const float* __restrict__ z,
                                             const float* __restrict__ Wc1,
                                             const float* __restrict__ bc1,
                                             float* __restrict__ a1) {
    __shared__ float zs[1024];
    __shared__ float red[256];
    const int b = blockIdx.y, j0 = blockIdx.x * 64;
    const int tid = threadIdx.x, tj = tid & 63, seg = tid >> 6;
    for (int t = tid; t < 1024; t += 256) zs[t] = z[b * 1024 + t];
    __syncthreads();
    float acc = 0.f;
    #pragma unroll 8
    for (int c = seg * 256; c < seg * 256 + 256; ++c)
        acc += zs[c] * Wc1[(size_t)c * 512 + j0 + tj];
    red[tid] = acc;
    __syncthreads();
    if (seg == 0) {
        float s = red[tj] + red[64 + tj] + red[128 + tj] + red[192 + tj] + bc1[j0 + tj];
        a1[b * 512 + j0 + tj] = fmaxf(s, 0.f);
    }
}

__global__ void k_fc2(const float* __restrict__ a1, const float* __restrict__ Wc2,
                      const float* __restrict__ bc2, float* __restrict__ out) {
    const int j = blockIdx.x, b = blockIdx.y, lane = threadIdx.x;
    float acc = 0.f;
    #pragma unroll
    for (int c8 = 0; c8 < 8; ++c8) {
        int c = c8 * 64 + lane;
        acc += a1[b * 512 + c] * Wc2[(size_t)c * 40 + j];
    }
    #pragma unroll
    for (int off = 32; off > 0; off >>= 1) acc += __shfl_xor(acc, off, 64);
    if (lane == 0) out[b * 40 + j] = acc + bc2[j];
}

extern "C" void kernel_launch(void* const* d_in, const int* in_sizes, int n_in,
                              void* d_out, int out_size, void* d_ws, size_t ws_size,
                              hipStream_t stream) {
    const float* pos = (const float*)d_in[0];
    const float* Wc1 = (const float*)d_in[17];
    const float* bc1 = (const float*)d_in[18];
    const float* Wc2 = (const float*)d_in[19];
    const float* bc2 = (const float*)d_in[20];

    char* p = (char*)d_ws;
    auto alloc = [&](size_t bytes) -> void* {
        void* r = (void*)p;
        p += (bytes + 255) & ~(size_t)255;
        return r;
    };
    float*    Dm   = (float*) alloc((size_t)BB * NN * NN * 4);   // 64 MB; aliased as Ufull(bf16) in L4
    unsigned short* Vfull = (unsigned short*)alloc((size_t)BN * 1024 * 2);  // 32 MB bf16 V
    void*     bufA = alloc((size_t)BN * 64 * 8);    // Ud (L1-3)
    void*     bufB = alloc((size_t)BN * 64 * 8);    // Vd
    void*     bufC = alloc((size_t)BN * 64 * 8);    // Hmin (L1-3) / Ybf fp32 (L4)
    double*   Ya   = (double*)alloc((size_t)BN * 64 * 8);
    double*   Yb   = (double*)alloc((size_t)BN * 128 * 8);
    float*    Yaf  = (float*) alloc((size_t)BN * 64 * 4);
    double*   Xd   = (double*)alloc((size_t)BN * 3 * 8);
    double*   SQd  = (double*)alloc((size_t)BN * 8);
    float*    SQf  = (float*) alloc((size_t)BN * 4);
    int*      IDX  = (int*)   alloc((size_t)BN * KK * 4);
    unsigned short* Xbf = (unsigned short*)alloc((size_t)BN * 128 * 2);  // 4 MB bf16 X
    unsigned short* Wtb = (unsigned short*)alloc((size_t)1024 * 128 * 2);
    unsigned short* Wdb = (unsigned short*)alloc((size_t)1024 * 128 * 2);
    double*   PARTS= (double*)alloc((size_t)4096 * 64 * 8);
    double*   PARTQ= (double*)alloc((size_t)4096 * 64 * 8);
    double*   PS2  = (double*)alloc((size_t)64 * 128 * 8);
    double*   PQ2  = (double*)alloc((size_t)64 * 128 * 8);
    double*   PL4S = (double*)alloc((size_t)2048 * 1024 * 8);  // 16 MB (2048 partial rows)
    double*   PL4Q = (double*)alloc((size_t)2048 * 1024 * 8);
    double*   PL4S2= (double*)alloc((size_t)32 * 1024 * 8);
    double*   PL4Q2= (double*)alloc((size_t)32 * 1024 * 8);
    double*   Sd   = (double*)alloc((size_t)128 * 8);
    double*   Td   = (double*)alloc((size_t)128 * 8);
    float*    Sf   = (float*) alloc((size_t)1024 * 4);
    float*    Tf   = (float*) alloc((size_t)1024 * 4);
    unsigned* Zmax = (unsigned*)alloc((size_t)BB * 1024 * 4);
    unsigned* Zmin = (unsigned*)alloc((size_t)BB * 1024 * 4);
    float*    Z    = (float*) alloc((size_t)BB * 1024 * 4);
    float*    A1   = (float*) alloc((size_t)BB * 512 * 4);
    // total ~= 207 MB (ws = 256 MiB)

    double* Ud = (double*)bufA; double* Vd = (double*)bufB; double* Hd = (double*)bufC;
    float*  Ybf = (float*)bufC;
    unsigned short* Ufull = (unsigned short*)Dm;  // D dead after L4 select; reuse (needs 32 MB)

    hipMemsetAsync(Zmax, 0x00, (size_t)BB * 1024 * 4, stream);
    hipMemsetAsync(Zmin, 0xFF, (size_t)BB * 1024 * 4, stream);

    k_cast3<<<(BN + 255) / 256, 256, 0, stream>>>(pos, Xd, SQd, SQf);
    k_wprep<<<dim3(16, 4), 256, 0, stream>>>((const float*)d_in[13], Wtb, Wdb);

    // ---- Layer 1: C=3 -> 64 ----
    {
        const float* W = (const float*)d_in[1], *bs = (const float*)d_in[2];
        const float* g = (const float*)d_in[3], *be = (const float*)d_in[4];
        k_dist<3><<<dim3(136, 1, BB), 256, 0, stream>>>(pos, SQf, Dm);
        k_select<3><<<dim3(NN / 4, BB), 256, 0, stream>>>(Dm, Xd, SQd, IDX);
        k_uv_d<3><<<BN / 16, 256, 0, stream>>>(Xd, W, bs, Ud, Vd, 64, 0);
        k_gath13<<<BN / 16, 256, 0, stream>>>(IDX, Ud, Vd, Hd, PARTS, PARTQ);
        k_bnred1<64><<<64, 256, 0, stream>>>(PARTS, PARTQ, PS2, PQ2);
        k_bnfin2_d<64><<<1, 256, 0, stream>>>(PS2, PQ2, g, be, Sd, Td, 0, 64);
        k_applyprep_d<<<BN, 64, 0, stream>>>(Ud, Hd, Sd, Td, Ya, Yaf, SQd, SQf);
    }
    // ---- Layer 2: C=64 -> 64 ----
    {
        const float* W = (const float*)d_in[5], *bs = (const float*)d_in[6];
        const float* g = (const float*)d_in[7], *be = (const float*)d_in[8];
        k_dist<64><<<dim3(136, 1, BB), 256, 0, stream>>>(Yaf, SQf, Dm);
        k_select<64><<<dim3(NN / 4, BB), 256, 0, stream>>>(Dm, Ya, SQd, IDX);
        k_uv_d<64><<<BN / 16, 256, 0, stream>>>(Ya, W, bs, Ud, Vd, 64, 0);
        k_gath13<<<BN / 16, 256, 0, stream>>>(IDX, Ud, Vd, Hd, PARTS, PARTQ);
        k_bnred1<64><<<64, 256, 0, stream>>>(PARTS, PARTQ, PS2, PQ2);
        k_bnfin2_d<64><<<1, 256, 0, stream>>>(PS2, PQ2, g, be, Sd, Td, 0, 64);
        k_applyprep_d<<<BN, 64, 0, stream>>>(Ud, Hd, Sd, Td, Ya, Yaf, SQd, SQf);
    }
    // ---- Layer 3: C=64 -> 128, two 64-col chunks, Ya -> Yb ----
    {
        const float* W = (const float*)d_in[9], *bs = (const float*)d_in[10];
        const float* g = (const float*)d_in[11], *be = (const float*)d_in[12];
        k_dist<64><<<dim3(136, 1, BB), 256, 0, stream>>>(Yaf, SQf, Dm);
        k_select<64><<<dim3(NN / 4, BB), 256, 0, stream>>>(Dm, Ya, SQd, IDX);
        for (int cc = 0; cc < 2; ++cc) {
            const int c0 = cc * 64;
            k_uv_d<64><<<BN / 16, 256, 0, stream>>>(Ya, W, bs, Ud, Vd, 128, c0);
            k_gath13<<<BN / 16, 256, 0, stream>>>(IDX, Ud, Vd, Hd, PARTS, PARTQ);
            k_bnred1<64><<<64, 256, 0, stream>>>(PARTS, PARTQ, PS2, PQ2);
            k_bnfin2_d<64><<<1, 256, 0, stream>>>(PS2, PQ2, g, be, Sd, Td, c0, 64);
            k_apply_d<<<BN, 64, 0, stream>>>(Ud, Hd, Sd, Td, Yb, 128, c0);
        }
        k_prep<<<BN / 4, 256, 0, stream>>>(Yb, Ybf, SQd, SQf, 128);   // Ybf = bufC
    }
    // ---- Layer 4: C=128 -> 1024, bf16 MFMA UV (bf16 out) + single-pass gather ----
    {
        const float* bs = (const float*)d_in[14];
        const float* g = (const float*)d_in[15], *be = (const float*)d_in[16];
        k_dist<128><<<dim3(136, 1, BB), 256, 0, stream>>>(Ybf, SQf, Dm);
        k_select<128><<<dim3(NN / 4, BB), 256, 0, stream>>>(Dm, Yb, SQd, IDX);
        k_xcast<<<BN * 128 / 2048, 256, 0, stream>>>(Yb, Xbf);
        // Dm is now dead -> Ufull (bf16) aliases it
        k_uv_mfma<<<dim3(32, BN / 64), 256, 0, stream>>>(Xbf, Wtb, Wdb, bs, Ufull, Vfull);
        k_gath4<<<2048, 256, 0, stream>>>(IDX, Ufull, Vfull, Zmax, Zmin, PL4S, PL4Q);
        k_bnred1_L4<<<128, 256, 0, stream>>>(PL4S, PL4Q, PL4S2, PL4Q2);
        k_bnfin_L4<<<4, 256, 0, stream>>>(PL4S2, PL4Q2, g, be, Sf, Tf);
        k_zfin<<<dim3(16, BB), 64, 0, stream>>>(Zmax, Zmin, Sf, Tf, Z);
    }

    k_fc1<<<dim3(8, BB), 256, 0, stream>>>(Z, Wc1, bc1, A1);
    k_fc2<<<dim3(40, BB), 64, 0, stream>>>(A1, Wc2, bc2, (float*)d_out);
}